// Round 14
// baseline (378.505 us; speedup 1.0000x reference)
//
#include <hip/hip_runtime.h>
#include <hip/hip_bf16.h>
#include <math.h>

// Problem constants (fixed by reference)
#define BB   8
#define LL   512
#define DD   512
#define GG   8
#define SSS  4
#define FGC  4
#define FEC  64
#define EEC  32
#define DHC  256
#define RHC  256
#define NT   (BB*LL)   // 4096 tokens
#define TM   32        // tokens per expert tile
#define TR   8         // tokens per fused_route block

#define XC_STRIDE 264  // shorts per k8 group (32*8 + 8 pad; 528 B, 16B-aligned)
#define CPAD 32        // ints per counter: one counter per 128B cache line
#define EGRID 1024     // expert kernel grid (128 blocks per XCD chunk)
#define RBLK 512       // route blocks in combined kernel (NT/TR)
#define PBLK 4096      // pack blocks in combined kernel (1M threads / 256)

typedef __attribute__((ext_vector_type(8))) short short8;
typedef __attribute__((ext_vector_type(4))) float floatx4;

__device__ __forceinline__ float gelu_exact(float x) {
    return 0.5f * x * (1.0f + erff(x * 0.70710678118654752440f));
}

// HW packed fp32->bf16 RNE (v_cvt_pk_bf16_f32); low 16 bits = first arg
__device__ __forceinline__ unsigned pk2(float a, float b) {
    union { __hip_bfloat162 h; unsigned u; } cv;
    cv.h = __float22bfloat162_rn(make_float2(a, b));
    return cv.u;
}
union U4S8 { unsigned u[4]; short8 s; };

__device__ __forceinline__ floatx4 mfma16(short8 a, short8 b, floatx4 c) {
    return __builtin_amdgcn_mfma_f32_16x16x32_bf16(a, b, c, 0, 0, 0);
}

// ---------------------------------------------------------------------------
// Prep: WinT[d][gs] = Win_h[g][d][s]   (coalesced ilog weight rows)
//       M2[g][f][s] = sum_e Wfe[g][f][e]*Win_f[g][e][s]
//       c2b[gs]     = sum_e bfe[g][e]*Win_f[g][e][s] + bin_b[gs]
//       block 65: zero counts + tokdone (replaces the memset launch)
// (R13 lesson: fusing this into route lengthens route's critical path and
//  costs more than the launch saves — keep it a separate tiny kernel.)
// ---------------------------------------------------------------------------
__global__ __launch_bounds__(256) void prep_kernel(
    const float* __restrict__ Win_h, const float* __restrict__ Win_f,
    const float* __restrict__ Wfe, const float* __restrict__ bfe,
    const float* __restrict__ bin_b,
    float* __restrict__ WinT, float* __restrict__ M2, float* __restrict__ c2b,
    int* __restrict__ counts_zero)
{
    const int tid = threadIdx.x;
    if (blockIdx.x < 64) {
        int idx = blockIdx.x * 256 + tid;      // d*32 + gs
        int d = idx >> 5, gs = idx & 31;
        int g = gs >> 2, s = gs & 3;
        WinT[idx] = Win_h[(size_t)g*DD*SSS + d*SSS + s];
    } else if (blockIdx.x == 64) {
        if (tid < GG*FGC*SSS) {                // 128: (g,f,s)
            int g = tid >> 4, f = (tid >> 2) & 3, s = tid & 3;
            float acc = 0.f;
            for (int e = 0; e < FEC; ++e)
                acc += Wfe[(size_t)g*FGC*FEC + f*FEC + e] * Win_f[(size_t)g*FEC*SSS + e*SSS + s];
            M2[tid] = acc;
        } else if (tid < GG*FGC*SSS + GG*SSS) {  // 32: gs
            int gs = tid - GG*FGC*SSS;
            int g = gs >> 2, s = gs & 3;
            float acc = bin_b[gs];
            for (int e = 0; e < FEC; ++e)
                acc += bfe[g*FEC + e] * Win_f[(size_t)g*FEC*SSS + e*SSS + s];
            c2b[gs] = acc;
        }
    } else {
        // zero counts (EEC*CPAD ints) + tokdone (NT ints, contiguous after)
        for (int i = tid; i < EEC*CPAD + NT; i += 256) counts_zero[i] = 0;
    }
}

// ---------------------------------------------------------------------------
// Combined route + weight-pack kernel (256 threads) — R12-exact (85 us):
//   blocks [0, RBLK):   routing (R4 compute body — verified local optimum).
//   blocks [RBLK, ...): pack We1/We2 -> bf16 MFMA B-fragment order; fills
//     the memory pipes the latency-bound route blocks leave idle.
// No worklist tail (R12 lesson: fence+done-counter cost > launch saved;
// expert blocks derive the partition from counts themselves).
// ---------------------------------------------------------------------------
__global__ __launch_bounds__(256) void route_and_pack(
    const float* __restrict__ hidden, const float* __restrict__ feat,
    const float* __restrict__ Wr1, const float* __restrict__ br1,
    const float* __restrict__ Wr2, const float* __restrict__ br2,
    const float* __restrict__ WinT, const float* __restrict__ M2,
    const float* __restrict__ c2b,
    int* __restrict__ bucket_tok, float* __restrict__ bucket_w,
    int* __restrict__ counts, int* __restrict__ nslot,
    const float* __restrict__ We1, const float* __restrict__ We2,
    short* __restrict__ Wp1, short* __restrict__ Wp2)
{
    const int tid = threadIdx.x;

    if (blockIdx.x >= RBLK) {
        // ---------------- pack body ----------------
        const int gid = (blockIdx.x - RBLK) * 256 + tid;
        if (gid < EEC*16*16*64) {            // We1 fragments
            const int lane = gid & 63;
            const int nb   = (gid >> 6) & 15;
            const int i    = (gid >> 10) & 15;
            const int e    = gid >> 14;
            const int k0   = i*32 + (lane >> 4)*8;
            const int n    = nb*16 + (lane & 15);
            const float* s = We1 + ((size_t)e*DD + k0)*DHC + n;
            float f[8];
            #pragma unroll
            for (int j = 0; j < 8; ++j) f[j] = s[(size_t)j*DHC];
            U4S8 cv;
            cv.u[0] = pk2(f[0], f[1]); cv.u[1] = pk2(f[2], f[3]);
            cv.u[2] = pk2(f[4], f[5]); cv.u[3] = pk2(f[6], f[7]);
            *(short8*)(Wp1 + (size_t)gid*8) = cv.s;
        } else {                             // We2 fragments
            const int g2   = gid - EEC*16*16*64;
            const int lane = g2 & 63;
            const int nb   = (g2 >> 6) & 31;
            const int i    = (g2 >> 11) & 7;
            const int e    = g2 >> 14;
            const int k0   = i*32 + (lane >> 4)*8;
            const int n    = nb*16 + (lane & 15);
            const float* s = We2 + ((size_t)e*DHC + k0)*DD + n;
            float f[8];
            #pragma unroll
            for (int j = 0; j < 8; ++j) f[j] = s[(size_t)j*DD];
            U4S8 cv;
            cv.u[0] = pk2(f[0], f[1]); cv.u[1] = pk2(f[2], f[3]);
            cv.u[2] = pk2(f[4], f[5]); cv.u[3] = pk2(f[6], f[7]);
            *(short8*)(Wp2 + (size_t)g2*8) = cv.s;
        }
        return;
    }

    // ---------------- route body (R4-exact) ----------------
    const int t0 = blockIdx.x * TR;

    __shared__ float hs[TR][DD];        // 16 KB
    __shared__ float ghs[TR][RHC+4];    // 8.1 KB
    __shared__ float featb[TR][GG*FGC];
    __shared__ float glogp[TR][GG][4];  // 4-way K-split partials
    __shared__ float gwvb[TR][GG];
    __shared__ float scoreb[TR][GG];
    __shared__ float ilogb[TR][GG*SSS];
    __shared__ float cwvb[TR][GG*SSS];

    // stage hidden
    for (int i = tid; i < TR*DD; i += 256) {
        int r = i >> 9, c = i & 511;
        hs[r][c] = hidden[(size_t)(t0 + r)*DD + c];
    }
    if (tid < TR*GG*FGC) {   // 256
        int r = tid >> 5, c = tid & 31;
        featb[r][c] = feat[(t0 + r)*(GG*FGC) + c];
    }
    __syncthreads();

    if (tid < TR*GG) {       // score per (t,g)
        int t = tid >> 3, g = tid & 7;
        float s = 0.f;
        #pragma unroll
        for (int f = 0; f < FGC; ++f) s += fminf(fmaxf(featb[t][g*4+f], 0.f), 1.f);
        scoreb[t][g] = s * 0.25f;
    }

    // ---- gh: thread owns Wr1 column h=tid for all 8 tokens (R4-exact) ----
    {
        float acc[TR];
        float b = br1[tid];
        #pragma unroll
        for (int t = 0; t < TR; ++t) acc[t] = b;
        #pragma unroll 4
        for (int k = 0; k < DD; k += 4) {
            float w0 = Wr1[(size_t)k*RHC + tid];
            float w1 = Wr1[(size_t)(k+1)*RHC + tid];
            float w2 = Wr1[(size_t)(k+2)*RHC + tid];
            float w3 = Wr1[(size_t)(k+3)*RHC + tid];
            #pragma unroll
            for (int t = 0; t < TR; ++t) {
                float4 h = *(const float4*)(&hs[t][k]);
                acc[t] += h.x*w0 + h.y*w1 + h.z*w2 + h.w*w3;
            }
        }
        #pragma unroll
        for (int t = 0; t < TR; ++t) ghs[t][tid] = gelu_exact(acc[t]);
    }
    __syncthreads();

    // ---- glog: all 256 threads, thread = (t, g, quarter of K) ----
    {
        const int t = tid >> 5, g = (tid >> 2) & 7, q = tid & 3;
        float s = (q == 0) ? br2[g] : 0.f;
        const float* wr = Wr2 + g;
        #pragma unroll 4
        for (int h = q*64; h < q*64 + 64; ++h) s += ghs[t][h] * wr[(size_t)h*GG];
        glogp[t][g][q] = s;
    }

    // ---- ilog: thread = (t = tid>>5, gs = tid&31) ----
    {
        const int t = tid >> 5, gs = tid & 31;
        const int g = gs >> 2, s = gs & 3;
        float acc = 0.f;
        #pragma unroll 8
        for (int k = 0; k < DD; ++k) acc += hs[t][k] * WinT[k*32 + gs];
        const float* m2 = M2 + g*16 + s;     // stride 4 over f
        acc += featb[t][g*4+0]*m2[0] + featb[t][g*4+1]*m2[4]
             + featb[t][g*4+2]*m2[8] + featb[t][g*4+3]*m2[12];
        const float centers[4] = {0.0f, 1.0f/3.0f, 2.0f/3.0f, 1.0f};
        float diff = scoreb[t][g] - centers[s];
        ilogb[t][gs] = acc + c2b[gs] - 16.0f * diff * diff;
    }
    __syncthreads();

    // group top-2 softmax per token
    if (tid < TR) {
        int t = tid;
        float gl[GG];
        #pragma unroll
        for (int g = 0; g < GG; ++g)
            gl[g] = glogp[t][g][0] + glogp[t][g][1] + glogp[t][g][2] + glogp[t][g][3];
        float a = -INFINITY, b = -INFINITY;
        #pragma unroll
        for (int g = 0; g < GG; ++g) {
            float v = gl[g];
            if (v > a) { b = a; a = v; } else if (v > b) { b = v; }
        }
        float thresh = b, m = a, sum = 0.f;
        float ex[GG];
        #pragma unroll
        for (int g = 0; g < GG; ++g) {
            ex[g] = (gl[g] >= thresh) ? __expf(gl[g] - m) : 0.f;
            sum += ex[g];
        }
        float inv = 1.0f / sum;
        #pragma unroll
        for (int g = 0; g < GG; ++g) gwvb[t][g] = ex[g] * inv;
    }
    // stage top-2 softmax per (t,g)
    if (tid < TR*GG) {
        int t = tid >> 3, g = tid & 7;
        float vv[4] = {ilogb[t][g*4+0], ilogb[t][g*4+1], ilogb[t][g*4+2], ilogb[t][g*4+3]};
        float a = -INFINITY, b = -INFINITY;
        #pragma unroll
        for (int s = 0; s < 4; ++s) {
            float v = vv[s];
            if (v > a) { b = a; a = v; } else if (v > b) { b = v; }
        }
        float thresh = b, m = a, sum = 0.f;
        float ex[4];
        #pragma unroll
        for (int s = 0; s < 4; ++s) {
            ex[s] = (vv[s] >= thresh) ? __expf(vv[s] - m) : 0.f;
            sum += ex[s];
        }
        float inv = 1.0f / sum;
        #pragma unroll
        for (int s = 0; s < 4; ++s) cwvb[t][g*4 + s] = ex[s] * inv;
    }
    __syncthreads();

    if (tid < TR) {
        int t = tid;
        int a = 0;
        for (int g = 0; g < GG; ++g) {
            float gw = gwvb[t][g];
            if (gw > 0.f) {
                for (int s = 0; s < SSS; ++s) {
                    float w = gw * cwvb[t][g*4 + s];
                    if (w > 0.f && a < 4) {
                        int ee = g*SSS + s;
                        int pos = atomicAdd(&counts[ee*CPAD], 1);
                        bucket_tok[ee*NT + pos] = ((t0 + t) << 2) | a;
                        bucket_w[ee*NT + pos]   = w;
                        ++a;
                    }
                }
            }
        }
        nslot[t0 + t] = a;
    }
}

// ---------------------------------------------------------------------------
// Expert GEMM v8: worklist-free partition derive (R12) + bijective chunked
// XCD mapping (R11) + FUSED y-reduction: after each tile's partial stores,
// threadfence-release + per-token done-counters (spread over 512 lines, <=4
// increments each); the block completing a token's LAST slot reduces its
// <=4 partial rows into y. Every token emits >=1 slot (top-group weight
// >= 1/8, top-stage >= 1/4 => w >= 1/32 > 0), so y is fully written.
// Canonical CUDA threadFenceReduction pattern.
// ---------------------------------------------------------------------------
__global__ __launch_bounds__(256) void expert_mfma8(
    const float* __restrict__ hidden,
    const short* __restrict__ Wp1, const float* __restrict__ be1,
    const short* __restrict__ Wp2, const float* __restrict__ be2,
    const int* __restrict__ bucket_tok, const float* __restrict__ bucket_w,
    const int* __restrict__ counts, const int* __restrict__ nslot,
    int* __restrict__ tokdone,
    float* __restrict__ y_part, float* __restrict__ y)
{
    const int tid  = threadIdx.x;
    const int wave = tid >> 6;
    const int lane = tid & 63;
    const int lm   = lane & 15;
    const int quad = lane >> 4;

    __shared__ short Xp[64 * XC_STRIDE];   // full X tile: 64 k8 x 32 m x 8
    __shared__ short Hp[32 * XC_STRIDE];   // H: 32 h8 x 32 m x 8
    __shared__ int   toks[TM];             // raw (tok<<2)|a
    __shared__ float tws[TM];
    __shared__ int   red_tok[TM];          // tokens this block must reduce
    __shared__ int   s_cnt[EEC], s_off[EEC + 1];

    // derive the (expert, tile) partition from counts — no worklist needed
    if (tid < EEC) s_cnt[tid] = counts[tid*CPAD];
    __syncthreads();
    if (tid == 0) {
        int acc = 0;
        #pragma unroll
        for (int e = 0; e < EEC; ++e) {
            s_off[e] = acc;
            acc += (s_cnt[e] + TM - 1) / TM;
        }
        s_off[EEC] = acc;
    }
    __syncthreads();
    const int NW = s_off[EEC];

    // bijective chunked split of [0,NW) over 8 XCD classes
    const int q    = NW >> 3, r = NW & 7;
    const int xcd  = blockIdx.x & 7;
    const int rank = blockIdx.x >> 3;            // 0..EGRID/8-1
    const int len  = q + (xcd < r ? 1 : 0);
    const int base = (xcd < r) ? xcd*(q+1) : r*(q+1) + (xcd - r)*q;

    for (int j = rank; j < len; j += (EGRID >> 3)) {
        const int it = base + j;
        int e = 0;
        while (e < EEC - 1 && it >= s_off[e + 1]) ++e;
        const int tile = it - s_off[e];
        const int cnt  = s_cnt[e];
        const int r0   = tile * TM;
        const int nrow = min(TM, cnt - r0);

        const short* W1 = Wp1 + (size_t)e * (16*16*64*8);
        const short* W2 = Wp2 + (size_t)e * (8*32*64*8);

        if (tid < TM) {
            if (tid < nrow) {
                toks[tid] = bucket_tok[e*NT + r0 + tid];
                tws[tid]  = bucket_w[e*NT + r0 + tid];
            } else { toks[tid] = -1; tws[tid] = 0.f; }
        }

        // prefetch phase-1 i=0 weights (independent of LDS) -> hides under X stage
        short8 b1c[4];
        {
            const short* wb = W1 + ((size_t)wave*4)*512 + lane*8;
            #pragma unroll
            for (int nb = 0; nb < 4; ++nb) b1c[nb] = *(const short8*)(wb + nb*512);
        }
        __syncthreads();

        // stage ALL of X (32 tok x 512 k) as bf16 in A-layout
        {
            const int xr = tid >> 3;      // token 0..31
            const int xk = tid & 7;       // k8 subgroup
            const int bt = toks[xr];
            const float* src = hidden + (size_t)(bt < 0 ? 0 : (bt >> 2))*DD;
            #pragma unroll
            for (int i = 0; i < 8; ++i) {
                const int k8 = xk + 8*i;
                float4 v0 = make_float4(0.f,0.f,0.f,0.f), v1 = v0;
                if (bt >= 0) {
                    v0 = *(const float4*)(src + k8*8);
                    v1 = *(const float4*)(src + k8*8 + 4);
                }
                U4S8 cv;
                cv.u[0] = pk2(v0.x, v0.y); cv.u[1] = pk2(v0.z, v0.w);
                cv.u[2] = pk2(v1.x, v1.y); cv.u[3] = pk2(v1.z, v1.w);
                *(short8*)(&Xp[k8 * XC_STRIDE + xr * 8]) = cv.s;
            }
        }
        __syncthreads();

        // ---- phase 1: H = gelu(X @ We1 + be1); wave owns 64 cols ----
        floatx4 acc[2][4];
        #pragma unroll
        for (int mb = 0; mb < 2; ++mb)
            #pragma unroll
            for (int nb = 0; nb < 4; ++nb)
                acc[mb][nb] = (floatx4){0.f, 0.f, 0.f, 0.f};

        for (int i = 0; i < 16; ++i) {
            const int k8 = i*4 + quad;
            short8 b1n[4];
            if (i < 15) {
                const short* wb = W1 + ((size_t)(i+1)*16 + wave*4)*512 + lane*8;
                #pragma unroll
                for (int nb = 0; nb < 4; ++nb) b1n[nb] = *(const short8*)(wb + nb*512);
            }
            short8 a0 = *(const short8*)(&Xp[k8 * XC_STRIDE + lm * 8]);
            short8 a1 = *(const short8*)(&Xp[k8 * XC_STRIDE + (16 + lm) * 8]);
            #pragma unroll
            for (int nb = 0; nb < 4; ++nb) {
                acc[0][nb] = mfma16(a0, b1c[nb], acc[0][nb]);
                acc[1][nb] = mfma16(a1, b1c[nb], acc[1][nb]);
            }
            if (i < 15) {
                #pragma unroll
                for (int nb = 0; nb < 4; ++nb) b1c[nb] = b1n[nb];
            }
        }

        // prefetch phase-2 i=0 weights -> hides under gelu epilogue
        short8 b2c[8];
        {
            const short* wb = W2 + ((size_t)wave*8)*512 + lane*8;
            #pragma unroll
            for (int nb = 0; nb < 8; ++nb) b2c[nb] = *(const short8*)(wb + nb*512);
        }

        // bias + gelu -> Hp (A-layout); waves write disjoint h-slices
        #pragma unroll
        for (int nb = 0; nb < 4; ++nb) {
            const int h = wave*64 + nb*16 + lm;
            const float b1 = be1[e*DHC + h];
            #pragma unroll
            for (int mb = 0; mb < 2; ++mb) {
                #pragma unroll
                for (int r2 = 0; r2 < 4; r2 += 2) {
                    const int m0 = mb*16 + quad*4 + r2;
                    unsigned u = pk2(gelu_exact(acc[mb][nb][r2]   + b1),
                                     gelu_exact(acc[mb][nb][r2+1] + b1));
                    Hp[(h >> 3) * XC_STRIDE + m0 * 8 + (h & 7)]     = (short)(u & 0xffff);
                    Hp[(h >> 3) * XC_STRIDE + (m0+1) * 8 + (h & 7)] = (short)(u >> 16);
                }
            }
        }
        __syncthreads();

        // ---- phase 2: Ypart = w*(H @ We2 + be2); wave owns 128 cols ----
        floatx4 c[2][8];
        #pragma unroll
        for (int mb = 0; mb < 2; ++mb)
            #pragma unroll
            for (int nb = 0; nb < 8; ++nb)
                c[mb][nb] = (floatx4){0.f, 0.f, 0.f, 0.f};

        for (int i = 0; i < 8; ++i) {
            const int k8 = i*4 + quad;
            short8 b2n[8];
            if (i < 7) {
                const short* wb = W2 + ((size_t)(i+1)*32 + wave*8)*512 + lane*8;
                #pragma unroll
                for (int nb = 0; nb < 8; ++nb) b2n[nb] = *(const short8*)(wb + nb*512);
            }
            short8 a0 = *(const short8*)(&Hp[k8 * XC_STRIDE + lm * 8]);
            short8 a1 = *(const short8*)(&Hp[k8 * XC_STRIDE + (16 + lm) * 8]);
            #pragma unroll
            for (int nb = 0; nb < 8; ++nb) {
                c[0][nb] = mfma16(a0, b2c[nb], c[0][nb]);
                c[1][nb] = mfma16(a1, b2c[nb], c[1][nb]);
            }
            if (i < 7) {
                #pragma unroll
                for (int nb = 0; nb < 8; ++nb) b2c[nb] = b2n[nb];
            }
        }

        // epilogue: weighted PLAIN stores into y_part (disjoint slots, no races)
        #pragma unroll
        for (int nb = 0; nb < 8; ++nb) {
            const int col = wave*128 + nb*16 + lm;
            const float b2 = be2[e*DD + col];
            #pragma unroll
            for (int mb = 0; mb < 2; ++mb) {
                #pragma unroll
                for (int r2 = 0; r2 < 4; ++r2) {
                    const int m = mb*16 + quad*4 + r2;
                    const int bt = toks[m];
                    if (bt >= 0)
                        y_part[(size_t)bt*DD + col] = tws[m] * (c[mb][nb][r2] + b2);
                }
            }
        }

        // ---- fused y-reduction (threadFenceReduction pattern) ----
        __syncthreads();          // all partial stores issued
        __threadfence();          // release: each thread's stores visible device-wide
        __syncthreads();          // all threads' fences complete before the atomics
        if (tid < TM) {
            int flag = -1;
            const int bt = toks[tid];
            if (bt >= 0) {
                const int t  = bt >> 2;
                const int ns = nslot[t];
                if (atomicAdd(&tokdone[t], 1) == ns - 1) flag = t;  // last slot
            }
            red_tok[tid] = flag;
        }
        __syncthreads();
        __threadfence();          // acquire: see other blocks' released stores
        for (int m = 0; m < TM; ++m) {
            const int t = red_tok[m];
            if (t < 0) continue;
            const int ns = nslot[t];
            if (tid < 128) {      // 128 float4 = 512 cols
                const float* p = y_part + ((size_t)t*4)*DD + tid*4;
                float4 s = make_float4(0.f, 0.f, 0.f, 0.f);
                for (int a = 0; a < ns; ++a) {
                    float4 v = *(const float4*)(p + (size_t)a*DD);
                    s.x += v.x; s.y += v.y; s.z += v.z; s.w += v.w;
                }
                *(float4*)(y + (size_t)t*DD + tid*4) = s;
            }
        }
        __syncthreads();   // protect toks/red_tok/Xp/Hp reuse across items
    }
}

// ---------------------------------------------------------------------------
// Legacy expert GEMM v3 (fallback, fp32 weights + y atomics).
// ---------------------------------------------------------------------------
__global__ __launch_bounds__(256) void expert_mfma3(
    const float* __restrict__ hidden,
    const float* __restrict__ We1, const float* __restrict__ be1,
    const float* __restrict__ We2, const float* __restrict__ be2,
    const int* __restrict__ bucket_tok, const float* __restrict__ bucket_w,
    const int* __restrict__ counts,
    float* __restrict__ y)
{
    const int e    = blockIdx.x & 31;
    const int tile = blockIdx.x >> 5;
    const int cnt  = counts[e*CPAD];
    const int r0   = tile * TM;
    if (r0 >= cnt) return;
    const int nrow = min(TM, cnt - r0);
    const int tid  = threadIdx.x;
    const int wave = tid >> 6;
    const int lane = tid & 63;
    const int lm   = lane & 15;
    const int quad = lane >> 4;

    __shared__ short Xp[64 * XC_STRIDE];
    __shared__ short Hp[32 * XC_STRIDE];
    __shared__ int   toks[TM];
    __shared__ float tws[TM];

    if (tid < TM) {
        if (tid < nrow) {
            toks[tid] = bucket_tok[e*NT + r0 + tid] >> 2;   // decode token
            tws[tid]  = bucket_w[e*NT + r0 + tid];
        } else { toks[tid] = -1; tws[tid] = 0.f; }
    }
    __syncthreads();

    {
        const int xr = tid >> 3;
        const int xk = tid & 7;
        const int tk = toks[xr];
        const float* src = hidden + (size_t)(tk < 0 ? 0 : tk)*DD;
        #pragma unroll
        for (int i = 0; i < 8; ++i) {
            const int k8 = xk + 8*i;
            float4 v0 = make_float4(0.f,0.f,0.f,0.f), v1 = v0;
            if (tk >= 0) {
                v0 = *(const float4*)(src + k8*8);
                v1 = *(const float4*)(src + k8*8 + 4);
            }
            U4S8 cv;
            cv.u[0] = pk2(v0.x, v0.y); cv.u[1] = pk2(v0.z, v0.w);
            cv.u[2] = pk2(v1.x, v1.y); cv.u[3] = pk2(v1.z, v1.w);
            *(short8*)(&Xp[k8 * XC_STRIDE + xr * 8]) = cv.s;
        }
    }
    __syncthreads();

    floatx4 acc[2][4];
    #pragma unroll
    for (int mb = 0; mb < 2; ++mb)
        #pragma unroll
        for (int nb = 0; nb < 4; ++nb)
            acc[mb][nb] = (floatx4){0.f, 0.f, 0.f, 0.f};

    const float* W1 = We1 + (size_t)e * DD * DHC;

    for (int i = 0; i < 16; ++i) {
        const int k8 = i*4 + quad;
        short8 a0 = *(const short8*)(&Xp[k8 * XC_STRIDE + lm * 8]);
        short8 a1 = *(const short8*)(&Xp[k8 * XC_STRIDE + (16 + lm) * 8]);
        float wreg[4][8];
        #pragma unroll
        for (int nb = 0; nb < 4; ++nb) {
            const float* s = W1 + (size_t)(k8*8)*DHC + wave*64 + nb*16 + lm;
            #pragma unroll
            for (int j = 0; j < 8; ++j) wreg[nb][j] = s[(size_t)j*DHC];
        }
        #pragma unroll
        for (int nb = 0; nb < 4; ++nb) {
            U4S8 cv;
            cv.u[0] = pk2(wreg[nb][0], wreg[nb][1]);
            cv.u[1] = pk2(wreg[nb][2], wreg[nb][3]);
            cv.u[2] = pk2(wreg[nb][4], wreg[nb][5]);
            cv.u[3] = pk2(wreg[nb][6], wreg[nb][7]);
            acc[0][nb] = mfma16(a0, cv.s, acc[0][nb]);
            acc[1][nb] = mfma16(a1, cv.s, acc[1][nb]);
        }
    }

    #pragma unroll
    for (int nb = 0; nb < 4; ++nb) {
        const int h = wave*64 + nb*16 + lm;
        const float b1 = be1[e*DHC + h];
        #pragma unroll
        for (int mb = 0; mb < 2; ++mb) {
            #pragma unroll
            for (int r = 0; r < 4; r += 2) {
                const int m0 = mb*16 + quad*4 + r;
                unsigned u = pk2(gelu_exact(acc[mb][nb][r]   + b1),
                                 gelu_exact(acc[mb][nb][r+1] + b1));
                Hp[(h >> 3) * XC_STRIDE + m0 * 8 + (h & 7)]     = (short)(u & 0xffff);
                Hp[(h >> 3) * XC_STRIDE + (m0+1) * 8 + (h & 7)] = (short)(u >> 16);
            }
        }
    }
    __syncthreads();

    floatx4 c[2][8];
    #pragma unroll
    for (int mb = 0; mb < 2; ++mb)
        #pragma unroll
        for (int nb = 0; nb < 8; ++nb)
            c[mb][nb] = (floatx4){0.f, 0.f, 0.f, 0.f};

    const float* W2 = We2 + (size_t)e * DHC * DD;

    for (int i = 0; i < 8; ++i) {
        const int k8 = i*4 + quad;
        short8 a0 = *(const short8*)(&Hp[k8 * XC_STRIDE + lm * 8]);
        short8 a1 = *(const short8*)(&Hp[k8 * XC_STRIDE + (16 + lm) * 8]);
        #pragma unroll
        for (int half = 0; half < 2; ++half) {
            float wreg[4][8];
            #pragma unroll
            for (int nb4 = 0; nb4 < 4; ++nb4) {
                const int n = wave*128 + (half*4 + nb4)*16 + lm;
                const float* s = W2 + (size_t)(k8*8)*DD + n;
                #pragma unroll
                for (int j = 0; j < 8; ++j) wreg[nb4][j] = s[(size_t)j*DD];
            }
            #pragma unroll
            for (int nb4 = 0; nb4 < 4; ++nb4) {
                const int nb = half*4 + nb4;
                U4S8 cv;
                cv.u[0] = pk2(wreg[nb4][0], wreg[nb4][1]);
                cv.u[1] = pk2(wreg[nb4][2], wreg[nb4][3]);
                cv.u[2] = pk2(wreg[nb4][4], wreg[nb4][5]);
                cv.u[3] = pk2(wreg[nb4][6], wreg[nb4][7]);
                c[0][nb] = mfma16(a0, cv.s, c[0][nb]);
                c[1][nb] = mfma16(a1, cv.s, c[1][nb]);
            }
        }
    }

    #pragma unroll
    for (int nb = 0; nb < 8; ++nb) {
        const int col = wave*128 + nb*16 + lm;
        const float b2 = be2[e*DD + col];
        #pragma unroll
        for (int mb = 0; mb < 2; ++mb) {
            #pragma unroll
            for (int r = 0; r < 4; ++r) {
                const int m = mb*16 + quad*4 + r;
                const int tk = toks[m];
                if (tk >= 0)
                    atomicAdd(&y[(size_t)tk*DD + col], tws[m] * (c[mb][nb][r] + b2));
            }
        }
    }
}

extern "C" void kernel_launch(void* const* d_in, const int* in_sizes, int n_in,
                              void* d_out, int out_size, void* d_ws, size_t ws_size,
                              hipStream_t stream) {
    const float* hidden = (const float*)d_in[0];
    const float* feat   = (const float*)d_in[1];
    // d_in[2] = valid_mask (unused)
    const float* Wr1    = (const float*)d_in[3];
    const float* br1    = (const float*)d_in[4];
    const float* Wr2    = (const float*)d_in[5];
    const float* br2    = (const float*)d_in[6];
    const float* Wfe    = (const float*)d_in[7];
    const float* bfe    = (const float*)d_in[8];
    const float* Win_h  = (const float*)d_in[9];
    const float* Win_f  = (const float*)d_in[10];
    const float* bin_b  = (const float*)d_in[11];
    const float* We1    = (const float*)d_in[12];
    const float* be1    = (const float*)d_in[13];
    const float* We2    = (const float*)d_in[14];
    const float* be2    = (const float*)d_in[15];
    float* y = (float*)d_out;

    // workspace layout
    char* ws = (char*)d_ws;
    int*   bucket_tok = (int*)ws;    ws += (size_t)EEC*NT*sizeof(int);      // 512 KB
    float* bucket_w   = (float*)ws;  ws += (size_t)EEC*NT*sizeof(float);    // 512 KB
    int*   counts     = (int*)ws;    ws += (size_t)EEC*CPAD*sizeof(int);    // 4 KB (padded)
    int*   tokdone    = (int*)ws;    ws += (size_t)NT*sizeof(int);          // 16 KB (after counts!)
    float* WinT       = (float*)ws;  ws += (size_t)DD*EEC*sizeof(float);    // 64 KB
    float* M2         = (float*)ws;  ws += 512;
    float* c2b        = (float*)ws;  ws += 256;
    int*   nslot      = (int*)ws;    ws += (size_t)NT*sizeof(int);          // 16 KB
    size_t base_used  = (size_t)(ws - (char*)d_ws);

    // fast-path extras: packed bf16 weights (16 MB) + fp32 partials (32 MB)
    short* Wp1    = (short*)ws;
    short* Wp2    = Wp1 + (size_t)EEC*DD*DHC;
    float* y_part = (float*)(Wp2 + (size_t)EEC*DHC*DD);
    size_t need_fast = base_used
                     + 2*(size_t)EEC*DD*DHC*sizeof(short)
                     + (size_t)NT*4*DD*sizeof(float);
    const bool fast = (ws_size >= need_fast);

    // prep also zeros counts+tokdone (block 65) — no memset launch needed
    prep_kernel<<<66, 256, 0, stream>>>(Win_h, Win_f, Wfe, bfe, bin_b,
                                        WinT, M2, c2b, counts);

    if (fast) {
        // route blocks [0,512) + pack blocks [512,4608), 256 threads each.
        route_and_pack<<<RBLK + PBLK, 256, 0, stream>>>(
            hidden, feat, Wr1, br1, Wr2, br2, WinT, M2, c2b,
            bucket_tok, bucket_w, counts, nslot,
            We1, We2, Wp1, Wp2);

        // expert GEMM with fused y-reduction (no reduce_y launch)
        expert_mfma8<<<EGRID, 256, 0, stream>>>(hidden, Wp1, be1, Wp2, be2,
                                                bucket_tok, bucket_w, counts,
                                                nslot, tokdone, y_part, y);
    } else {
        hipMemsetAsync(y, 0, (size_t)NT*DD*sizeof(float), stream);

        // route only (no pack blocks); Wp pointers unused.
        route_and_pack<<<RBLK, 256, 0, stream>>>(
            hidden, feat, Wr1, br1, Wr2, br2, WinT, M2, c2b,
            bucket_tok, bucket_w, counts, nslot,
            We1, We2, (short*)nullptr, (short*)nullptr);

        expert_mfma3<<<(NT/TM)*EEC, 256, 0, stream>>>(hidden, We1, be1, We2, be2,
                                                      bucket_tok, bucket_w, counts, y);
    }
}

// Round 15
// 245.244 us; speedup vs baseline: 1.5434x; 1.5434x over previous
//
#include <hip/hip_runtime.h>
#include <hip/hip_bf16.h>
#include <math.h>

// Problem constants (fixed by reference)
#define BB   8
#define LL   512
#define DD   512
#define GG   8
#define SSS  4
#define FGC  4
#define FEC  64
#define EEC  32
#define DHC  256
#define RHC  256
#define NT   (BB*LL)   // 4096 tokens
#define TM   32        // tokens per expert tile
#define TR   8         // tokens per fused_route block

#define XC_STRIDE 264  // shorts per k8 group (32*8 + 8 pad; 528 B, 16B-aligned)
#define CPAD 32        // ints per counter: one counter per 128B cache line
#define EGRID 1024     // expert kernel grid (128 blocks per XCD chunk)
#define RBLK 512       // route blocks in combined kernel (NT/TR)
#define PBLK 4096      // pack blocks in combined kernel (1M threads / 256)

typedef __attribute__((ext_vector_type(8))) short short8;
typedef __attribute__((ext_vector_type(4))) float floatx4;

__device__ __forceinline__ float gelu_exact(float x) {
    return 0.5f * x * (1.0f + erff(x * 0.70710678118654752440f));
}

// HW packed fp32->bf16 RNE (v_cvt_pk_bf16_f32); low 16 bits = first arg
__device__ __forceinline__ unsigned pk2(float a, float b) {
    union { __hip_bfloat162 h; unsigned u; } cv;
    cv.h = __float22bfloat162_rn(make_float2(a, b));
    return cv.u;
}
union U4S8 { unsigned u[4]; short8 s; };

__device__ __forceinline__ floatx4 mfma16(short8 a, short8 b, floatx4 c) {
    return __builtin_amdgcn_mfma_f32_16x16x32_bf16(a, b, c, 0, 0, 0);
}

// ---------------------------------------------------------------------------
// Prep: WinT[d][gs] = Win_h[g][d][s]   (coalesced ilog weight rows)
//       M2[g][f][s] = sum_e Wfe[g][f][e]*Win_f[g][e][s]
//       c2b[gs]     = sum_e bfe[g][e]*Win_f[g][e][s] + bin_b[gs]
//       block 65: zero counts (replaces the memset launch)
// Session law (R13/R14): keep prep separate — fusing it into route extends
// route's critical path; fusing reductions/fences into throughput kernels
// drains their load pipelines. Only sync-free fusions (pack, memset) pay.
// ---------------------------------------------------------------------------
__global__ __launch_bounds__(256) void prep_kernel(
    const float* __restrict__ Win_h, const float* __restrict__ Win_f,
    const float* __restrict__ Wfe, const float* __restrict__ bfe,
    const float* __restrict__ bin_b,
    float* __restrict__ WinT, float* __restrict__ M2, float* __restrict__ c2b,
    int* __restrict__ counts_zero)
{
    const int tid = threadIdx.x;
    if (blockIdx.x < 64) {
        int idx = blockIdx.x * 256 + tid;      // d*32 + gs
        int d = idx >> 5, gs = idx & 31;
        int g = gs >> 2, s = gs & 3;
        WinT[idx] = Win_h[(size_t)g*DD*SSS + d*SSS + s];
    } else if (blockIdx.x == 64) {
        if (tid < GG*FGC*SSS) {                // 128: (g,f,s)
            int g = tid >> 4, f = (tid >> 2) & 3, s = tid & 3;
            float acc = 0.f;
            for (int e = 0; e < FEC; ++e)
                acc += Wfe[(size_t)g*FGC*FEC + f*FEC + e] * Win_f[(size_t)g*FEC*SSS + e*SSS + s];
            M2[tid] = acc;
        } else if (tid < GG*FGC*SSS + GG*SSS) {  // 32: gs
            int gs = tid - GG*FGC*SSS;
            int g = gs >> 2, s = gs & 3;
            float acc = bin_b[gs];
            for (int e = 0; e < FEC; ++e)
                acc += bfe[g*FEC + e] * Win_f[(size_t)g*FEC*SSS + e*SSS + s];
            c2b[gs] = acc;
        }
    } else {
        for (int i = tid; i < EEC*CPAD; i += 256) counts_zero[i] = 0;
    }
}

// ---------------------------------------------------------------------------
// Combined route + weight-pack kernel (256 threads):
//   blocks [0, RBLK):   routing (R4 body — verified local optimum; every
//     rewrite regressed — do not touch). No worklist tail (R12 lesson).
//   blocks [RBLK, ...): pack We1/We2 -> bf16 MFMA B-fragment order; fills
//     the memory pipes the latency-bound route blocks leave idle.
// ---------------------------------------------------------------------------
__global__ __launch_bounds__(256) void route_and_pack(
    const float* __restrict__ hidden, const float* __restrict__ feat,
    const float* __restrict__ Wr1, const float* __restrict__ br1,
    const float* __restrict__ Wr2, const float* __restrict__ br2,
    const float* __restrict__ WinT, const float* __restrict__ M2,
    const float* __restrict__ c2b,
    int* __restrict__ bucket_tok, float* __restrict__ bucket_w,
    int* __restrict__ counts, int* __restrict__ nslot,
    const float* __restrict__ We1, const float* __restrict__ We2,
    short* __restrict__ Wp1, short* __restrict__ Wp2)
{
    const int tid = threadIdx.x;

    if (blockIdx.x >= RBLK) {
        // ---------------- pack body ----------------
        const int gid = (blockIdx.x - RBLK) * 256 + tid;
        if (gid < EEC*16*16*64) {            // We1 fragments
            const int lane = gid & 63;
            const int nb   = (gid >> 6) & 15;
            const int i    = (gid >> 10) & 15;
            const int e    = gid >> 14;
            const int k0   = i*32 + (lane >> 4)*8;
            const int n    = nb*16 + (lane & 15);
            const float* s = We1 + ((size_t)e*DD + k0)*DHC + n;
            float f[8];
            #pragma unroll
            for (int j = 0; j < 8; ++j) f[j] = s[(size_t)j*DHC];
            U4S8 cv;
            cv.u[0] = pk2(f[0], f[1]); cv.u[1] = pk2(f[2], f[3]);
            cv.u[2] = pk2(f[4], f[5]); cv.u[3] = pk2(f[6], f[7]);
            *(short8*)(Wp1 + (size_t)gid*8) = cv.s;
        } else {                             // We2 fragments
            const int g2   = gid - EEC*16*16*64;
            const int lane = g2 & 63;
            const int nb   = (g2 >> 6) & 31;
            const int i    = (g2 >> 11) & 7;
            const int e    = g2 >> 14;
            const int k0   = i*32 + (lane >> 4)*8;
            const int n    = nb*16 + (lane & 15);
            const float* s = We2 + ((size_t)e*DHC + k0)*DD + n;
            float f[8];
            #pragma unroll
            for (int j = 0; j < 8; ++j) f[j] = s[(size_t)j*DD];
            U4S8 cv;
            cv.u[0] = pk2(f[0], f[1]); cv.u[1] = pk2(f[2], f[3]);
            cv.u[2] = pk2(f[4], f[5]); cv.u[3] = pk2(f[6], f[7]);
            *(short8*)(Wp2 + (size_t)g2*8) = cv.s;
        }
        return;
    }

    // ---------------- route body (R4-exact) ----------------
    const int t0 = blockIdx.x * TR;

    __shared__ float hs[TR][DD];        // 16 KB
    __shared__ float ghs[TR][RHC+4];    // 8.1 KB
    __shared__ float featb[TR][GG*FGC];
    __shared__ float glogp[TR][GG][4];  // 4-way K-split partials
    __shared__ float gwvb[TR][GG];
    __shared__ float scoreb[TR][GG];
    __shared__ float ilogb[TR][GG*SSS];
    __shared__ float cwvb[TR][GG*SSS];

    // stage hidden
    for (int i = tid; i < TR*DD; i += 256) {
        int r = i >> 9, c = i & 511;
        hs[r][c] = hidden[(size_t)(t0 + r)*DD + c];
    }
    if (tid < TR*GG*FGC) {   // 256
        int r = tid >> 5, c = tid & 31;
        featb[r][c] = feat[(t0 + r)*(GG*FGC) + c];
    }
    __syncthreads();

    if (tid < TR*GG) {       // score per (t,g)
        int t = tid >> 3, g = tid & 7;
        float s = 0.f;
        #pragma unroll
        for (int f = 0; f < FGC; ++f) s += fminf(fmaxf(featb[t][g*4+f], 0.f), 1.f);
        scoreb[t][g] = s * 0.25f;
    }

    // ---- gh: thread owns Wr1 column h=tid for all 8 tokens (R4-exact) ----
    {
        float acc[TR];
        float b = br1[tid];
        #pragma unroll
        for (int t = 0; t < TR; ++t) acc[t] = b;
        #pragma unroll 4
        for (int k = 0; k < DD; k += 4) {
            float w0 = Wr1[(size_t)k*RHC + tid];
            float w1 = Wr1[(size_t)(k+1)*RHC + tid];
            float w2 = Wr1[(size_t)(k+2)*RHC + tid];
            float w3 = Wr1[(size_t)(k+3)*RHC + tid];
            #pragma unroll
            for (int t = 0; t < TR; ++t) {
                float4 h = *(const float4*)(&hs[t][k]);
                acc[t] += h.x*w0 + h.y*w1 + h.z*w2 + h.w*w3;
            }
        }
        #pragma unroll
        for (int t = 0; t < TR; ++t) ghs[t][tid] = gelu_exact(acc[t]);
    }
    __syncthreads();

    // ---- glog: all 256 threads, thread = (t, g, quarter of K) ----
    {
        const int t = tid >> 5, g = (tid >> 2) & 7, q = tid & 3;
        float s = (q == 0) ? br2[g] : 0.f;
        const float* wr = Wr2 + g;
        #pragma unroll 4
        for (int h = q*64; h < q*64 + 64; ++h) s += ghs[t][h] * wr[(size_t)h*GG];
        glogp[t][g][q] = s;
    }

    // ---- ilog: thread = (t = tid>>5, gs = tid&31) ----
    {
        const int t = tid >> 5, gs = tid & 31;
        const int g = gs >> 2, s = gs & 3;
        float acc = 0.f;
        #pragma unroll 8
        for (int k = 0; k < DD; ++k) acc += hs[t][k] * WinT[k*32 + gs];
        const float* m2 = M2 + g*16 + s;     // stride 4 over f
        acc += featb[t][g*4+0]*m2[0] + featb[t][g*4+1]*m2[4]
             + featb[t][g*4+2]*m2[8] + featb[t][g*4+3]*m2[12];
        const float centers[4] = {0.0f, 1.0f/3.0f, 2.0f/3.0f, 1.0f};
        float diff = scoreb[t][g] - centers[s];
        ilogb[t][gs] = acc + c2b[gs] - 16.0f * diff * diff;
    }
    __syncthreads();

    // group top-2 softmax per token
    if (tid < TR) {
        int t = tid;
        float gl[GG];
        #pragma unroll
        for (int g = 0; g < GG; ++g)
            gl[g] = glogp[t][g][0] + glogp[t][g][1] + glogp[t][g][2] + glogp[t][g][3];
        float a = -INFINITY, b = -INFINITY;
        #pragma unroll
        for (int g = 0; g < GG; ++g) {
            float v = gl[g];
            if (v > a) { b = a; a = v; } else if (v > b) { b = v; }
        }
        float thresh = b, m = a, sum = 0.f;
        float ex[GG];
        #pragma unroll
        for (int g = 0; g < GG; ++g) {
            ex[g] = (gl[g] >= thresh) ? __expf(gl[g] - m) : 0.f;
            sum += ex[g];
        }
        float inv = 1.0f / sum;
        #pragma unroll
        for (int g = 0; g < GG; ++g) gwvb[t][g] = ex[g] * inv;
    }
    // stage top-2 softmax per (t,g)
    if (tid < TR*GG) {
        int t = tid >> 3, g = tid & 7;
        float vv[4] = {ilogb[t][g*4+0], ilogb[t][g*4+1], ilogb[t][g*4+2], ilogb[t][g*4+3]};
        float a = -INFINITY, b = -INFINITY;
        #pragma unroll
        for (int s = 0; s < 4; ++s) {
            float v = vv[s];
            if (v > a) { b = a; a = v; } else if (v > b) { b = v; }
        }
        float thresh = b, m = a, sum = 0.f;
        float ex[4];
        #pragma unroll
        for (int s = 0; s < 4; ++s) {
            ex[s] = (vv[s] >= thresh) ? __expf(vv[s] - m) : 0.f;
            sum += ex[s];
        }
        float inv = 1.0f / sum;
        #pragma unroll
        for (int s = 0; s < 4; ++s) cwvb[t][g*4 + s] = ex[s] * inv;
    }
    __syncthreads();

    if (tid < TR) {
        int t = tid;
        int a = 0;
        for (int g = 0; g < GG; ++g) {
            float gw = gwvb[t][g];
            if (gw > 0.f) {
                for (int s = 0; s < SSS; ++s) {
                    float w = gw * cwvb[t][g*4 + s];
                    if (w > 0.f && a < 4) {
                        int ee = g*SSS + s;
                        int pos = atomicAdd(&counts[ee*CPAD], 1);
                        bucket_tok[ee*NT + pos] = ((t0 + t) << 2) | a;
                        bucket_w[ee*NT + pos]   = w;
                        ++a;
                    }
                }
            }
        }
        nslot[t0 + t] = a;
    }
}

// ---------------------------------------------------------------------------
// Expert GEMM v7 (R12-exact): worklist-free partition derive + bijective
// chunked XCD mapping. No fences anywhere.
// ---------------------------------------------------------------------------
__global__ __launch_bounds__(256) void expert_mfma7(
    const float* __restrict__ hidden,
    const short* __restrict__ Wp1, const float* __restrict__ be1,
    const short* __restrict__ Wp2, const float* __restrict__ be2,
    const int* __restrict__ bucket_tok, const float* __restrict__ bucket_w,
    const int* __restrict__ counts,
    float* __restrict__ y_part)
{
    const int tid  = threadIdx.x;
    const int wave = tid >> 6;
    const int lane = tid & 63;
    const int lm   = lane & 15;
    const int quad = lane >> 4;

    __shared__ short Xp[64 * XC_STRIDE];   // full X tile: 64 k8 x 32 m x 8
    __shared__ short Hp[32 * XC_STRIDE];   // H: 32 h8 x 32 m x 8
    __shared__ int   toks[TM];             // raw (tok<<2)|a
    __shared__ float tws[TM];
    __shared__ int   s_cnt[EEC], s_off[EEC + 1];

    // derive the (expert, tile) partition from counts — no worklist needed
    if (tid < EEC) s_cnt[tid] = counts[tid*CPAD];
    __syncthreads();
    if (tid == 0) {
        int acc = 0;
        #pragma unroll
        for (int e = 0; e < EEC; ++e) {
            s_off[e] = acc;
            acc += (s_cnt[e] + TM - 1) / TM;
        }
        s_off[EEC] = acc;
    }
    __syncthreads();
    const int NW = s_off[EEC];

    // bijective chunked split of [0,NW) over 8 XCD classes
    const int q    = NW >> 3, r = NW & 7;
    const int xcd  = blockIdx.x & 7;
    const int rank = blockIdx.x >> 3;            // 0..EGRID/8-1
    const int len  = q + (xcd < r ? 1 : 0);
    const int base = (xcd < r) ? xcd*(q+1) : r*(q+1) + (xcd - r)*q;

    for (int j = rank; j < len; j += (EGRID >> 3)) {
        const int it = base + j;
        int e = 0;
        while (e < EEC - 1 && it >= s_off[e + 1]) ++e;
        const int tile = it - s_off[e];
        const int cnt  = s_cnt[e];
        const int r0   = tile * TM;
        const int nrow = min(TM, cnt - r0);

        const short* W1 = Wp1 + (size_t)e * (16*16*64*8);
        const short* W2 = Wp2 + (size_t)e * (8*32*64*8);

        if (tid < TM) {
            if (tid < nrow) {
                toks[tid] = bucket_tok[e*NT + r0 + tid];
                tws[tid]  = bucket_w[e*NT + r0 + tid];
            } else { toks[tid] = -1; tws[tid] = 0.f; }
        }

        // prefetch phase-1 i=0 weights (independent of LDS) -> hides under X stage
        short8 b1c[4];
        {
            const short* wb = W1 + ((size_t)wave*4)*512 + lane*8;
            #pragma unroll
            for (int nb = 0; nb < 4; ++nb) b1c[nb] = *(const short8*)(wb + nb*512);
        }
        __syncthreads();

        // stage ALL of X (32 tok x 512 k) as bf16 in A-layout
        {
            const int xr = tid >> 3;      // token 0..31
            const int xk = tid & 7;       // k8 subgroup
            const int bt = toks[xr];
            const float* src = hidden + (size_t)(bt < 0 ? 0 : (bt >> 2))*DD;
            #pragma unroll
            for (int i = 0; i < 8; ++i) {
                const int k8 = xk + 8*i;
                float4 v0 = make_float4(0.f,0.f,0.f,0.f), v1 = v0;
                if (bt >= 0) {
                    v0 = *(const float4*)(src + k8*8);
                    v1 = *(const float4*)(src + k8*8 + 4);
                }
                U4S8 cv;
                cv.u[0] = pk2(v0.x, v0.y); cv.u[1] = pk2(v0.z, v0.w);
                cv.u[2] = pk2(v1.x, v1.y); cv.u[3] = pk2(v1.z, v1.w);
                *(short8*)(&Xp[k8 * XC_STRIDE + xr * 8]) = cv.s;
            }
        }
        __syncthreads();

        // ---- phase 1: H = gelu(X @ We1 + be1); wave owns 64 cols ----
        floatx4 acc[2][4];
        #pragma unroll
        for (int mb = 0; mb < 2; ++mb)
            #pragma unroll
            for (int nb = 0; nb < 4; ++nb)
                acc[mb][nb] = (floatx4){0.f, 0.f, 0.f, 0.f};

        for (int i = 0; i < 16; ++i) {
            const int k8 = i*4 + quad;
            short8 b1n[4];
            if (i < 15) {
                const short* wb = W1 + ((size_t)(i+1)*16 + wave*4)*512 + lane*8;
                #pragma unroll
                for (int nb = 0; nb < 4; ++nb) b1n[nb] = *(const short8*)(wb + nb*512);
            }
            short8 a0 = *(const short8*)(&Xp[k8 * XC_STRIDE + lm * 8]);
            short8 a1 = *(const short8*)(&Xp[k8 * XC_STRIDE + (16 + lm) * 8]);
            #pragma unroll
            for (int nb = 0; nb < 4; ++nb) {
                acc[0][nb] = mfma16(a0, b1c[nb], acc[0][nb]);
                acc[1][nb] = mfma16(a1, b1c[nb], acc[1][nb]);
            }
            if (i < 15) {
                #pragma unroll
                for (int nb = 0; nb < 4; ++nb) b1c[nb] = b1n[nb];
            }
        }

        // prefetch phase-2 i=0 weights -> hides under gelu epilogue
        short8 b2c[8];
        {
            const short* wb = W2 + ((size_t)wave*8)*512 + lane*8;
            #pragma unroll
            for (int nb = 0; nb < 8; ++nb) b2c[nb] = *(const short8*)(wb + nb*512);
        }

        // bias + gelu -> Hp (A-layout); waves write disjoint h-slices
        #pragma unroll
        for (int nb = 0; nb < 4; ++nb) {
            const int h = wave*64 + nb*16 + lm;
            const float b1 = be1[e*DHC + h];
            #pragma unroll
            for (int mb = 0; mb < 2; ++mb) {
                #pragma unroll
                for (int r2 = 0; r2 < 4; r2 += 2) {
                    const int m0 = mb*16 + quad*4 + r2;
                    unsigned u = pk2(gelu_exact(acc[mb][nb][r2]   + b1),
                                     gelu_exact(acc[mb][nb][r2+1] + b1));
                    Hp[(h >> 3) * XC_STRIDE + m0 * 8 + (h & 7)]     = (short)(u & 0xffff);
                    Hp[(h >> 3) * XC_STRIDE + (m0+1) * 8 + (h & 7)] = (short)(u >> 16);
                }
            }
        }
        __syncthreads();

        // ---- phase 2: Ypart = w*(H @ We2 + be2); wave owns 128 cols ----
        floatx4 c[2][8];
        #pragma unroll
        for (int mb = 0; mb < 2; ++mb)
            #pragma unroll
            for (int nb = 0; nb < 8; ++nb)
                c[mb][nb] = (floatx4){0.f, 0.f, 0.f, 0.f};

        for (int i = 0; i < 8; ++i) {
            const int k8 = i*4 + quad;
            short8 b2n[8];
            if (i < 7) {
                const short* wb = W2 + ((size_t)(i+1)*32 + wave*8)*512 + lane*8;
                #pragma unroll
                for (int nb = 0; nb < 8; ++nb) b2n[nb] = *(const short8*)(wb + nb*512);
            }
            short8 a0 = *(const short8*)(&Hp[k8 * XC_STRIDE + lm * 8]);
            short8 a1 = *(const short8*)(&Hp[k8 * XC_STRIDE + (16 + lm) * 8]);
            #pragma unroll
            for (int nb = 0; nb < 8; ++nb) {
                c[0][nb] = mfma16(a0, b2c[nb], c[0][nb]);
                c[1][nb] = mfma16(a1, b2c[nb], c[1][nb]);
            }
            if (i < 7) {
                #pragma unroll
                for (int nb = 0; nb < 8; ++nb) b2c[nb] = b2n[nb];
            }
        }

        // epilogue: weighted PLAIN stores into y_part (disjoint slots, no races)
        #pragma unroll
        for (int nb = 0; nb < 8; ++nb) {
            const int col = wave*128 + nb*16 + lm;
            const float b2 = be2[e*DD + col];
            #pragma unroll
            for (int mb = 0; mb < 2; ++mb) {
                #pragma unroll
                for (int r2 = 0; r2 < 4; ++r2) {
                    const int m = mb*16 + quad*4 + r2;
                    const int bt = toks[m];
                    if (bt >= 0)
                        y_part[(size_t)bt*DD + col] = tws[m] * (c[mb][nb][r2] + b2);
                }
            }
        }
        __syncthreads();   // protect toks/Xp/Hp reuse across items
    }
}

// ---------------------------------------------------------------------------
// reduce_y: y[t][:] = sum over a < nslot[t] of y_part[t*4+a][:]
// ---------------------------------------------------------------------------
__global__ __launch_bounds__(256) void reduce_y(
    const float* __restrict__ y_part, const int* __restrict__ nslot,
    float* __restrict__ y)
{
    const int idx = blockIdx.x * 256 + threadIdx.x;   // float4 id, NT*128 total
    const int t  = idx >> 7;
    const int c4 = idx & 127;
    const int ns = nslot[t];
    float4 s = make_float4(0.f, 0.f, 0.f, 0.f);
    const float* p = y_part + ((size_t)t*4)*DD + c4*4;
    for (int a = 0; a < ns; ++a) {
        float4 v = *(const float4*)(p + (size_t)a*DD);
        s.x += v.x; s.y += v.y; s.z += v.z; s.w += v.w;
    }
    *(float4*)(y + (size_t)t*DD + c4*4) = s;
}

// ---------------------------------------------------------------------------
// Legacy expert GEMM v3 (fallback, fp32 weights + y atomics).
// ---------------------------------------------------------------------------
__global__ __launch_bounds__(256) void expert_mfma3(
    const float* __restrict__ hidden,
    const float* __restrict__ We1, const float* __restrict__ be1,
    const float* __restrict__ We2, const float* __restrict__ be2,
    const int* __restrict__ bucket_tok, const float* __restrict__ bucket_w,
    const int* __restrict__ counts,
    float* __restrict__ y)
{
    const int e    = blockIdx.x & 31;
    const int tile = blockIdx.x >> 5;
    const int cnt  = counts[e*CPAD];
    const int r0   = tile * TM;
    if (r0 >= cnt) return;
    const int nrow = min(TM, cnt - r0);
    const int tid  = threadIdx.x;
    const int wave = tid >> 6;
    const int lane = tid & 63;
    const int lm   = lane & 15;
    const int quad = lane >> 4;

    __shared__ short Xp[64 * XC_STRIDE];
    __shared__ short Hp[32 * XC_STRIDE];
    __shared__ int   toks[TM];
    __shared__ float tws[TM];

    if (tid < TM) {
        if (tid < nrow) {
            toks[tid] = bucket_tok[e*NT + r0 + tid] >> 2;   // decode token
            tws[tid]  = bucket_w[e*NT + r0 + tid];
        } else { toks[tid] = -1; tws[tid] = 0.f; }
    }
    __syncthreads();

    {
        const int xr = tid >> 3;
        const int xk = tid & 7;
        const int tk = toks[xr];
        const float* src = hidden + (size_t)(tk < 0 ? 0 : tk)*DD;
        #pragma unroll
        for (int i = 0; i < 8; ++i) {
            const int k8 = xk + 8*i;
            float4 v0 = make_float4(0.f,0.f,0.f,0.f), v1 = v0;
            if (tk >= 0) {
                v0 = *(const float4*)(src + k8*8);
                v1 = *(const float4*)(src + k8*8 + 4);
            }
            U4S8 cv;
            cv.u[0] = pk2(v0.x, v0.y); cv.u[1] = pk2(v0.z, v0.w);
            cv.u[2] = pk2(v1.x, v1.y); cv.u[3] = pk2(v1.z, v1.w);
            *(short8*)(&Xp[k8 * XC_STRIDE + xr * 8]) = cv.s;
        }
    }
    __syncthreads();

    floatx4 acc[2][4];
    #pragma unroll
    for (int mb = 0; mb < 2; ++mb)
        #pragma unroll
        for (int nb = 0; nb < 4; ++nb)
            acc[mb][nb] = (floatx4){0.f, 0.f, 0.f, 0.f};

    const float* W1 = We1 + (size_t)e * DD * DHC;

    for (int i = 0; i < 16; ++i) {
        const int k8 = i*4 + quad;
        short8 a0 = *(const short8*)(&Xp[k8 * XC_STRIDE + lm * 8]);
        short8 a1 = *(const short8*)(&Xp[k8 * XC_STRIDE + (16 + lm) * 8]);
        float wreg[4][8];
        #pragma unroll
        for (int nb = 0; nb < 4; ++nb) {
            const float* s = W1 + (size_t)(k8*8)*DHC + wave*64 + nb*16 + lm;
            #pragma unroll
            for (int j = 0; j < 8; ++j) wreg[nb][j] = s[(size_t)j*DHC];
        }
        #pragma unroll
        for (int nb = 0; nb < 4; ++nb) {
            U4S8 cv;
            cv.u[0] = pk2(wreg[nb][0], wreg[nb][1]);
            cv.u[1] = pk2(wreg[nb][2], wreg[nb][3]);
            cv.u[2] = pk2(wreg[nb][4], wreg[nb][5]);
            cv.u[3] = pk2(wreg[nb][6], wreg[nb][7]);
            acc[0][nb] = mfma16(a0, cv.s, acc[0][nb]);
            acc[1][nb] = mfma16(a1, cv.s, acc[1][nb]);
        }
    }

    #pragma unroll
    for (int nb = 0; nb < 4; ++nb) {
        const int h = wave*64 + nb*16 + lm;
        const float b1 = be1[e*DHC + h];
        #pragma unroll
        for (int mb = 0; mb < 2; ++mb) {
            #pragma unroll
            for (int r = 0; r < 4; r += 2) {
                const int m0 = mb*16 + quad*4 + r;
                unsigned u = pk2(gelu_exact(acc[mb][nb][r]   + b1),
                                 gelu_exact(acc[mb][nb][r+1] + b1));
                Hp[(h >> 3) * XC_STRIDE + m0 * 8 + (h & 7)]     = (short)(u & 0xffff);
                Hp[(h >> 3) * XC_STRIDE + (m0+1) * 8 + (h & 7)] = (short)(u >> 16);
            }
        }
    }
    __syncthreads();

    floatx4 c[2][8];
    #pragma unroll
    for (int mb = 0; mb < 2; ++mb)
        #pragma unroll
        for (int nb = 0; nb < 8; ++nb)
            c[mb][nb] = (floatx4){0.f, 0.f, 0.f, 0.f};

    const float* W2 = We2 + (size_t)e * DHC * DD;

    for (int i = 0; i < 8; ++i) {
        const int k8 = i*4 + quad;
        short8 a0 = *(const short8*)(&Hp[k8 * XC_STRIDE + lm * 8]);
        short8 a1 = *(const short8*)(&Hp[k8 * XC_STRIDE + (16 + lm) * 8]);
        #pragma unroll
        for (int half = 0; half < 2; ++half) {
            float wreg[4][8];
            #pragma unroll
            for (int nb4 = 0; nb4 < 4; ++nb4) {
                const int n = wave*128 + (half*4 + nb4)*16 + lm;
                const float* s = W2 + (size_t)(k8*8)*DD + n;
                #pragma unroll
                for (int j = 0; j < 8; ++j) wreg[nb4][j] = s[(size_t)j*DD];
            }
            #pragma unroll
            for (int nb4 = 0; nb4 < 4; ++nb4) {
                const int nb = half*4 + nb4;
                U4S8 cv;
                cv.u[0] = pk2(wreg[nb4][0], wreg[nb4][1]);
                cv.u[1] = pk2(wreg[nb4][2], wreg[nb4][3]);
                cv.u[2] = pk2(wreg[nb4][4], wreg[nb4][5]);
                cv.u[3] = pk2(wreg[nb4][6], wreg[nb4][7]);
                c[0][nb] = mfma16(a0, cv.s, c[0][nb]);
                c[1][nb] = mfma16(a1, cv.s, c[1][nb]);
            }
        }
    }

    #pragma unroll
    for (int nb = 0; nb < 8; ++nb) {
        const int col = wave*128 + nb*16 + lm;
        const float b2 = be2[e*DD + col];
        #pragma unroll
        for (int mb = 0; mb < 2; ++mb) {
            #pragma unroll
            for (int r = 0; r < 4; ++r) {
                const int m = mb*16 + quad*4 + r;
                const int tk = toks[m];
                if (tk >= 0)
                    atomicAdd(&y[(size_t)tk*DD + col], tws[m] * (c[mb][nb][r] + b2));
            }
        }
    }
}

extern "C" void kernel_launch(void* const* d_in, const int* in_sizes, int n_in,
                              void* d_out, int out_size, void* d_ws, size_t ws_size,
                              hipStream_t stream) {
    const float* hidden = (const float*)d_in[0];
    const float* feat   = (const float*)d_in[1];
    // d_in[2] = valid_mask (unused)
    const float* Wr1    = (const float*)d_in[3];
    const float* br1    = (const float*)d_in[4];
    const float* Wr2    = (const float*)d_in[5];
    const float* br2    = (const float*)d_in[6];
    const float* Wfe    = (const float*)d_in[7];
    const float* bfe    = (const float*)d_in[8];
    const float* Win_h  = (const float*)d_in[9];
    const float* Win_f  = (const float*)d_in[10];
    const float* bin_b  = (const float*)d_in[11];
    const float* We1    = (const float*)d_in[12];
    const float* be1    = (const float*)d_in[13];
    const float* We2    = (const float*)d_in[14];
    const float* be2    = (const float*)d_in[15];
    float* y = (float*)d_out;

    // workspace layout
    char* ws = (char*)d_ws;
    int*   bucket_tok = (int*)ws;    ws += (size_t)EEC*NT*sizeof(int);      // 512 KB
    float* bucket_w   = (float*)ws;  ws += (size_t)EEC*NT*sizeof(float);    // 512 KB
    int*   counts     = (int*)ws;    ws += (size_t)EEC*CPAD*sizeof(int);    // 4 KB (padded)
    float* WinT       = (float*)ws;  ws += (size_t)DD*EEC*sizeof(float);    // 64 KB
    float* M2         = (float*)ws;  ws += 512;
    float* c2b        = (float*)ws;  ws += 256;
    int*   nslot      = (int*)ws;    ws += (size_t)NT*sizeof(int);          // 16 KB
    size_t base_used  = (size_t)(ws - (char*)d_ws);

    // fast-path extras: packed bf16 weights (16 MB) + fp32 partials (32 MB)
    short* Wp1    = (short*)ws;
    short* Wp2    = Wp1 + (size_t)EEC*DD*DHC;
    float* y_part = (float*)(Wp2 + (size_t)EEC*DHC*DD);
    size_t need_fast = base_used
                     + 2*(size_t)EEC*DD*DHC*sizeof(short)
                     + (size_t)NT*4*DD*sizeof(float);
    const bool fast = (ws_size >= need_fast);

    // prep also zeros counts (block 65) — no memset launch needed
    prep_kernel<<<66, 256, 0, stream>>>(Win_h, Win_f, Wfe, bfe, bin_b,
                                        WinT, M2, c2b, counts);

    if (fast) {
        // route blocks [0,512) + pack blocks [512,4608), 256 threads each.
        route_and_pack<<<RBLK + PBLK, 256, 0, stream>>>(
            hidden, feat, Wr1, br1, Wr2, br2, WinT, M2, c2b,
            bucket_tok, bucket_w, counts, nslot,
            We1, We2, Wp1, Wp2);

        expert_mfma7<<<EGRID, 256, 0, stream>>>(hidden, Wp1, be1, Wp2, be2,
                                                bucket_tok, bucket_w, counts,
                                                y_part);

        reduce_y<<<(NT*DD/4)/256, 256, 0, stream>>>(y_part, nslot, y);
    } else {
        hipMemsetAsync(y, 0, (size_t)NT*DD*sizeof(float), stream);

        // route only (no pack blocks); Wp pointers unused.
        route_and_pack<<<RBLK, 256, 0, stream>>>(
            hidden, feat, Wr1, br1, Wr2, br2, WinT, M2, c2b,
            bucket_tok, bucket_w, counts, nslot,
            We1, We2, (short*)nullptr, (short*)nullptr);

        expert_mfma3<<<(NT/TM)*EEC, 256, 0, stream>>>(hidden, We1, be1, We2, be2,
                                                      bucket_tok, bucket_w, counts, y);
    }
}

// Round 16
// 244.153 us; speedup vs baseline: 1.5503x; 1.0045x over previous
//
#include <hip/hip_runtime.h>
#include <hip/hip_bf16.h>
#include <math.h>

// Problem constants (fixed by reference)
#define BB   8
#define LL   512
#define DD   512
#define GG   8
#define SSS  4
#define FGC  4
#define FEC  64
#define EEC  32
#define DHC  256
#define RHC  256
#define NT   (BB*LL)   // 4096 tokens
#define TM   32        // tokens per expert tile
#define TR   8         // tokens per fused_route block

#define XC_STRIDE 264  // shorts per k8 group (32*8 + 8 pad; 528 B, 16B-aligned)
#define CPAD 32        // ints per counter: one counter per 128B cache line
#define EGRID 512      // expert kernel grid (64 ranks per XCD; NW/8 ~ 68 items)
#define RBLK 512       // route blocks in combined kernel (NT/TR)
#define PBLK 4096      // pack blocks in combined kernel (1M threads / 256)
#define RGRID 1024     // reduce_y grid (grid-stride over NT*128 float4s)

typedef __attribute__((ext_vector_type(8))) short short8;
typedef __attribute__((ext_vector_type(4))) float floatx4;

__device__ __forceinline__ float gelu_exact(float x) {
    return 0.5f * x * (1.0f + erff(x * 0.70710678118654752440f));
}

// HW packed fp32->bf16 RNE (v_cvt_pk_bf16_f32); low 16 bits = first arg
__device__ __forceinline__ unsigned pk2(float a, float b) {
    union { __hip_bfloat162 h; unsigned u; } cv;
    cv.h = __float22bfloat162_rn(make_float2(a, b));
    return cv.u;
}
union U4S8 { unsigned u[4]; short8 s; };

__device__ __forceinline__ floatx4 mfma16(short8 a, short8 b, floatx4 c) {
    return __builtin_amdgcn_mfma_f32_16x16x32_bf16(a, b, c, 0, 0, 0);
}

// ---------------------------------------------------------------------------
// Prep: WinT[d][gs] = Win_h[g][d][s]   (coalesced ilog weight rows)
//       M2[g][f][s] = sum_e Wfe[g][f][e]*Win_f[g][e][s]
//       c2b[gs]     = sum_e bfe[g][e]*Win_f[g][e][s] + bin_b[gs]
//       block 65: zero counts (replaces the memset launch)
// Session law (R13/R14): keep prep separate — fusing it into route extends
// route's critical path; fusing reductions/fences into throughput kernels
// drains their load pipelines. Only sync-free fusions (pack, memset) pay.
// ---------------------------------------------------------------------------
__global__ __launch_bounds__(256) void prep_kernel(
    const float* __restrict__ Win_h, const float* __restrict__ Win_f,
    const float* __restrict__ Wfe, const float* __restrict__ bfe,
    const float* __restrict__ bin_b,
    float* __restrict__ WinT, float* __restrict__ M2, float* __restrict__ c2b,
    int* __restrict__ counts_zero)
{
    const int tid = threadIdx.x;
    if (blockIdx.x < 64) {
        int idx = blockIdx.x * 256 + tid;      // d*32 + gs
        int d = idx >> 5, gs = idx & 31;
        int g = gs >> 2, s = gs & 3;
        WinT[idx] = Win_h[(size_t)g*DD*SSS + d*SSS + s];
    } else if (blockIdx.x == 64) {
        if (tid < GG*FGC*SSS) {                // 128: (g,f,s)
            int g = tid >> 4, f = (tid >> 2) & 3, s = tid & 3;
            float acc = 0.f;
            for (int e = 0; e < FEC; ++e)
                acc += Wfe[(size_t)g*FGC*FEC + f*FEC + e] * Win_f[(size_t)g*FEC*SSS + e*SSS + s];
            M2[tid] = acc;
        } else if (tid < GG*FGC*SSS + GG*SSS) {  // 32: gs
            int gs = tid - GG*FGC*SSS;
            int g = gs >> 2, s = gs & 3;
            float acc = bin_b[gs];
            for (int e = 0; e < FEC; ++e)
                acc += bfe[g*FEC + e] * Win_f[(size_t)g*FEC*SSS + e*SSS + s];
            c2b[gs] = acc;
        }
    } else {
        for (int i = tid; i < EEC*CPAD; i += 256) counts_zero[i] = 0;
    }
}

// ---------------------------------------------------------------------------
// Combined route + weight-pack kernel (256 threads):
//   blocks [0, RBLK):   routing (R4 body — verified local optimum; every
//     rewrite regressed — do not touch). No worklist tail (R12 lesson).
//   blocks [RBLK, ...): pack We1/We2 -> bf16 MFMA B-fragment order; fills
//     the memory pipes the latency-bound route blocks leave idle.
// ---------------------------------------------------------------------------
__global__ __launch_bounds__(256) void route_and_pack(
    const float* __restrict__ hidden, const float* __restrict__ feat,
    const float* __restrict__ Wr1, const float* __restrict__ br1,
    const float* __restrict__ Wr2, const float* __restrict__ br2,
    const float* __restrict__ WinT, const float* __restrict__ M2,
    const float* __restrict__ c2b,
    int* __restrict__ bucket_tok, float* __restrict__ bucket_w,
    int* __restrict__ counts, int* __restrict__ nslot,
    const float* __restrict__ We1, const float* __restrict__ We2,
    short* __restrict__ Wp1, short* __restrict__ Wp2)
{
    const int tid = threadIdx.x;

    if (blockIdx.x >= RBLK) {
        // ---------------- pack body ----------------
        const int gid = (blockIdx.x - RBLK) * 256 + tid;
        if (gid < EEC*16*16*64) {            // We1 fragments
            const int lane = gid & 63;
            const int nb   = (gid >> 6) & 15;
            const int i    = (gid >> 10) & 15;
            const int e    = gid >> 14;
            const int k0   = i*32 + (lane >> 4)*8;
            const int n    = nb*16 + (lane & 15);
            const float* s = We1 + ((size_t)e*DD + k0)*DHC + n;
            float f[8];
            #pragma unroll
            for (int j = 0; j < 8; ++j) f[j] = s[(size_t)j*DHC];
            U4S8 cv;
            cv.u[0] = pk2(f[0], f[1]); cv.u[1] = pk2(f[2], f[3]);
            cv.u[2] = pk2(f[4], f[5]); cv.u[3] = pk2(f[6], f[7]);
            *(short8*)(Wp1 + (size_t)gid*8) = cv.s;
        } else {                             // We2 fragments
            const int g2   = gid - EEC*16*16*64;
            const int lane = g2 & 63;
            const int nb   = (g2 >> 6) & 31;
            const int i    = (g2 >> 11) & 7;
            const int e    = g2 >> 14;
            const int k0   = i*32 + (lane >> 4)*8;
            const int n    = nb*16 + (lane & 15);
            const float* s = We2 + ((size_t)e*DHC + k0)*DD + n;
            float f[8];
            #pragma unroll
            for (int j = 0; j < 8; ++j) f[j] = s[(size_t)j*DD];
            U4S8 cv;
            cv.u[0] = pk2(f[0], f[1]); cv.u[1] = pk2(f[2], f[3]);
            cv.u[2] = pk2(f[4], f[5]); cv.u[3] = pk2(f[6], f[7]);
            *(short8*)(Wp2 + (size_t)g2*8) = cv.s;
        }
        return;
    }

    // ---------------- route body (R4-exact) ----------------
    const int t0 = blockIdx.x * TR;

    __shared__ float hs[TR][DD];        // 16 KB
    __shared__ float ghs[TR][RHC+4];    // 8.1 KB
    __shared__ float featb[TR][GG*FGC];
    __shared__ float glogp[TR][GG][4];  // 4-way K-split partials
    __shared__ float gwvb[TR][GG];
    __shared__ float scoreb[TR][GG];
    __shared__ float ilogb[TR][GG*SSS];
    __shared__ float cwvb[TR][GG*SSS];

    // stage hidden
    for (int i = tid; i < TR*DD; i += 256) {
        int r = i >> 9, c = i & 511;
        hs[r][c] = hidden[(size_t)(t0 + r)*DD + c];
    }
    if (tid < TR*GG*FGC) {   // 256
        int r = tid >> 5, c = tid & 31;
        featb[r][c] = feat[(t0 + r)*(GG*FGC) + c];
    }
    __syncthreads();

    if (tid < TR*GG) {       // score per (t,g)
        int t = tid >> 3, g = tid & 7;
        float s = 0.f;
        #pragma unroll
        for (int f = 0; f < FGC; ++f) s += fminf(fmaxf(featb[t][g*4+f], 0.f), 1.f);
        scoreb[t][g] = s * 0.25f;
    }

    // ---- gh: thread owns Wr1 column h=tid for all 8 tokens (R4-exact) ----
    {
        float acc[TR];
        float b = br1[tid];
        #pragma unroll
        for (int t = 0; t < TR; ++t) acc[t] = b;
        #pragma unroll 4
        for (int k = 0; k < DD; k += 4) {
            float w0 = Wr1[(size_t)k*RHC + tid];
            float w1 = Wr1[(size_t)(k+1)*RHC + tid];
            float w2 = Wr1[(size_t)(k+2)*RHC + tid];
            float w3 = Wr1[(size_t)(k+3)*RHC + tid];
            #pragma unroll
            for (int t = 0; t < TR; ++t) {
                float4 h = *(const float4*)(&hs[t][k]);
                acc[t] += h.x*w0 + h.y*w1 + h.z*w2 + h.w*w3;
            }
        }
        #pragma unroll
        for (int t = 0; t < TR; ++t) ghs[t][tid] = gelu_exact(acc[t]);
    }
    __syncthreads();

    // ---- glog: all 256 threads, thread = (t, g, quarter of K) ----
    {
        const int t = tid >> 5, g = (tid >> 2) & 7, q = tid & 3;
        float s = (q == 0) ? br2[g] : 0.f;
        const float* wr = Wr2 + g;
        #pragma unroll 4
        for (int h = q*64; h < q*64 + 64; ++h) s += ghs[t][h] * wr[(size_t)h*GG];
        glogp[t][g][q] = s;
    }

    // ---- ilog: thread = (t = tid>>5, gs = tid&31) ----
    {
        const int t = tid >> 5, gs = tid & 31;
        const int g = gs >> 2, s = gs & 3;
        float acc = 0.f;
        #pragma unroll 8
        for (int k = 0; k < DD; ++k) acc += hs[t][k] * WinT[k*32 + gs];
        const float* m2 = M2 + g*16 + s;     // stride 4 over f
        acc += featb[t][g*4+0]*m2[0] + featb[t][g*4+1]*m2[4]
             + featb[t][g*4+2]*m2[8] + featb[t][g*4+3]*m2[12];
        const float centers[4] = {0.0f, 1.0f/3.0f, 2.0f/3.0f, 1.0f};
        float diff = scoreb[t][g] - centers[s];
        ilogb[t][gs] = acc + c2b[gs] - 16.0f * diff * diff;
    }
    __syncthreads();

    // group top-2 softmax per token
    if (tid < TR) {
        int t = tid;
        float gl[GG];
        #pragma unroll
        for (int g = 0; g < GG; ++g)
            gl[g] = glogp[t][g][0] + glogp[t][g][1] + glogp[t][g][2] + glogp[t][g][3];
        float a = -INFINITY, b = -INFINITY;
        #pragma unroll
        for (int g = 0; g < GG; ++g) {
            float v = gl[g];
            if (v > a) { b = a; a = v; } else if (v > b) { b = v; }
        }
        float thresh = b, m = a, sum = 0.f;
        float ex[GG];
        #pragma unroll
        for (int g = 0; g < GG; ++g) {
            ex[g] = (gl[g] >= thresh) ? __expf(gl[g] - m) : 0.f;
            sum += ex[g];
        }
        float inv = 1.0f / sum;
        #pragma unroll
        for (int g = 0; g < GG; ++g) gwvb[t][g] = ex[g] * inv;
    }
    // stage top-2 softmax per (t,g)
    if (tid < TR*GG) {
        int t = tid >> 3, g = tid & 7;
        float vv[4] = {ilogb[t][g*4+0], ilogb[t][g*4+1], ilogb[t][g*4+2], ilogb[t][g*4+3]};
        float a = -INFINITY, b = -INFINITY;
        #pragma unroll
        for (int s = 0; s < 4; ++s) {
            float v = vv[s];
            if (v > a) { b = a; a = v; } else if (v > b) { b = v; }
        }
        float thresh = b, m = a, sum = 0.f;
        float ex[4];
        #pragma unroll
        for (int s = 0; s < 4; ++s) {
            ex[s] = (vv[s] >= thresh) ? __expf(vv[s] - m) : 0.f;
            sum += ex[s];
        }
        float inv = 1.0f / sum;
        #pragma unroll
        for (int s = 0; s < 4; ++s) cwvb[t][g*4 + s] = ex[s] * inv;
    }
    __syncthreads();

    if (tid < TR) {
        int t = tid;
        int a = 0;
        for (int g = 0; g < GG; ++g) {
            float gw = gwvb[t][g];
            if (gw > 0.f) {
                for (int s = 0; s < SSS; ++s) {
                    float w = gw * cwvb[t][g*4 + s];
                    if (w > 0.f && a < 4) {
                        int ee = g*SSS + s;
                        int pos = atomicAdd(&counts[ee*CPAD], 1);
                        bucket_tok[ee*NT + pos] = ((t0 + t) << 2) | a;
                        bucket_w[ee*NT + pos]   = w;
                        ++a;
                    }
                }
            }
        }
        nslot[t0 + t] = a;
    }
}

// ---------------------------------------------------------------------------
// Expert GEMM v7: worklist-free partition derive + bijective chunked XCD
// mapping. EGRID=512: ~64 ranks/XCD for ~68 items/XCD -> near-zero idle
// blocks (at 1024, ~half the blocks ran the derive then exited).
// ---------------------------------------------------------------------------
__global__ __launch_bounds__(256) void expert_mfma7(
    const float* __restrict__ hidden,
    const short* __restrict__ Wp1, const float* __restrict__ be1,
    const short* __restrict__ Wp2, const float* __restrict__ be2,
    const int* __restrict__ bucket_tok, const float* __restrict__ bucket_w,
    const int* __restrict__ counts,
    float* __restrict__ y_part)
{
    const int tid  = threadIdx.x;
    const int wave = tid >> 6;
    const int lane = tid & 63;
    const int lm   = lane & 15;
    const int quad = lane >> 4;

    __shared__ short Xp[64 * XC_STRIDE];   // full X tile: 64 k8 x 32 m x 8
    __shared__ short Hp[32 * XC_STRIDE];   // H: 32 h8 x 32 m x 8
    __shared__ int   toks[TM];             // raw (tok<<2)|a
    __shared__ float tws[TM];
    __shared__ int   s_cnt[EEC], s_off[EEC + 1];

    // derive the (expert, tile) partition from counts — no worklist needed
    if (tid < EEC) s_cnt[tid] = counts[tid*CPAD];
    __syncthreads();
    if (tid == 0) {
        int acc = 0;
        #pragma unroll
        for (int e = 0; e < EEC; ++e) {
            s_off[e] = acc;
            acc += (s_cnt[e] + TM - 1) / TM;
        }
        s_off[EEC] = acc;
    }
    __syncthreads();
    const int NW = s_off[EEC];

    // bijective chunked split of [0,NW) over 8 XCD classes
    const int q    = NW >> 3, r = NW & 7;
    const int xcd  = blockIdx.x & 7;
    const int rank = blockIdx.x >> 3;            // 0..EGRID/8-1
    const int len  = q + (xcd < r ? 1 : 0);
    const int base = (xcd < r) ? xcd*(q+1) : r*(q+1) + (xcd - r)*q;

    for (int j = rank; j < len; j += (EGRID >> 3)) {
        const int it = base + j;
        int e = 0;
        while (e < EEC - 1 && it >= s_off[e + 1]) ++e;
        const int tile = it - s_off[e];
        const int cnt  = s_cnt[e];
        const int r0   = tile * TM;
        const int nrow = min(TM, cnt - r0);

        const short* W1 = Wp1 + (size_t)e * (16*16*64*8);
        const short* W2 = Wp2 + (size_t)e * (8*32*64*8);

        if (tid < TM) {
            if (tid < nrow) {
                toks[tid] = bucket_tok[e*NT + r0 + tid];
                tws[tid]  = bucket_w[e*NT + r0 + tid];
            } else { toks[tid] = -1; tws[tid] = 0.f; }
        }

        // prefetch phase-1 i=0 weights (independent of LDS) -> hides under X stage
        short8 b1c[4];
        {
            const short* wb = W1 + ((size_t)wave*4)*512 + lane*8;
            #pragma unroll
            for (int nb = 0; nb < 4; ++nb) b1c[nb] = *(const short8*)(wb + nb*512);
        }
        __syncthreads();

        // stage ALL of X (32 tok x 512 k) as bf16 in A-layout
        {
            const int xr = tid >> 3;      // token 0..31
            const int xk = tid & 7;       // k8 subgroup
            const int bt = toks[xr];
            const float* src = hidden + (size_t)(bt < 0 ? 0 : (bt >> 2))*DD;
            #pragma unroll
            for (int i = 0; i < 8; ++i) {
                const int k8 = xk + 8*i;
                float4 v0 = make_float4(0.f,0.f,0.f,0.f), v1 = v0;
                if (bt >= 0) {
                    v0 = *(const float4*)(src + k8*8);
                    v1 = *(const float4*)(src + k8*8 + 4);
                }
                U4S8 cv;
                cv.u[0] = pk2(v0.x, v0.y); cv.u[1] = pk2(v0.z, v0.w);
                cv.u[2] = pk2(v1.x, v1.y); cv.u[3] = pk2(v1.z, v1.w);
                *(short8*)(&Xp[k8 * XC_STRIDE + xr * 8]) = cv.s;
            }
        }
        __syncthreads();

        // ---- phase 1: H = gelu(X @ We1 + be1); wave owns 64 cols ----
        floatx4 acc[2][4];
        #pragma unroll
        for (int mb = 0; mb < 2; ++mb)
            #pragma unroll
            for (int nb = 0; nb < 4; ++nb)
                acc[mb][nb] = (floatx4){0.f, 0.f, 0.f, 0.f};

        for (int i = 0; i < 16; ++i) {
            const int k8 = i*4 + quad;
            short8 b1n[4];
            if (i < 15) {
                const short* wb = W1 + ((size_t)(i+1)*16 + wave*4)*512 + lane*8;
                #pragma unroll
                for (int nb = 0; nb < 4; ++nb) b1n[nb] = *(const short8*)(wb + nb*512);
            }
            short8 a0 = *(const short8*)(&Xp[k8 * XC_STRIDE + lm * 8]);
            short8 a1 = *(const short8*)(&Xp[k8 * XC_STRIDE + (16 + lm) * 8]);
            #pragma unroll
            for (int nb = 0; nb < 4; ++nb) {
                acc[0][nb] = mfma16(a0, b1c[nb], acc[0][nb]);
                acc[1][nb] = mfma16(a1, b1c[nb], acc[1][nb]);
            }
            if (i < 15) {
                #pragma unroll
                for (int nb = 0; nb < 4; ++nb) b1c[nb] = b1n[nb];
            }
        }

        // prefetch phase-2 i=0 weights -> hides under gelu epilogue
        short8 b2c[8];
        {
            const short* wb = W2 + ((size_t)wave*8)*512 + lane*8;
            #pragma unroll
            for (int nb = 0; nb < 8; ++nb) b2c[nb] = *(const short8*)(wb + nb*512);
        }

        // bias + gelu -> Hp (A-layout); waves write disjoint h-slices
        #pragma unroll
        for (int nb = 0; nb < 4; ++nb) {
            const int h = wave*64 + nb*16 + lm;
            const float b1 = be1[e*DHC + h];
            #pragma unroll
            for (int mb = 0; mb < 2; ++mb) {
                #pragma unroll
                for (int r2 = 0; r2 < 4; r2 += 2) {
                    const int m0 = mb*16 + quad*4 + r2;
                    unsigned u = pk2(gelu_exact(acc[mb][nb][r2]   + b1),
                                     gelu_exact(acc[mb][nb][r2+1] + b1));
                    Hp[(h >> 3) * XC_STRIDE + m0 * 8 + (h & 7)]     = (short)(u & 0xffff);
                    Hp[(h >> 3) * XC_STRIDE + (m0+1) * 8 + (h & 7)] = (short)(u >> 16);
                }
            }
        }
        __syncthreads();

        // ---- phase 2: Ypart = w*(H @ We2 + be2); wave owns 128 cols ----
        floatx4 c[2][8];
        #pragma unroll
        for (int mb = 0; mb < 2; ++mb)
            #pragma unroll
            for (int nb = 0; nb < 8; ++nb)
                c[mb][nb] = (floatx4){0.f, 0.f, 0.f, 0.f};

        for (int i = 0; i < 8; ++i) {
            const int k8 = i*4 + quad;
            short8 b2n[8];
            if (i < 7) {
                const short* wb = W2 + ((size_t)(i+1)*32 + wave*8)*512 + lane*8;
                #pragma unroll
                for (int nb = 0; nb < 8; ++nb) b2n[nb] = *(const short8*)(wb + nb*512);
            }
            short8 a0 = *(const short8*)(&Hp[k8 * XC_STRIDE + lm * 8]);
            short8 a1 = *(const short8*)(&Hp[k8 * XC_STRIDE + (16 + lm) * 8]);
            #pragma unroll
            for (int nb = 0; nb < 8; ++nb) {
                c[0][nb] = mfma16(a0, b2c[nb], c[0][nb]);
                c[1][nb] = mfma16(a1, b2c[nb], c[1][nb]);
            }
            if (i < 7) {
                #pragma unroll
                for (int nb = 0; nb < 8; ++nb) b2c[nb] = b2n[nb];
            }
        }

        // epilogue: weighted PLAIN stores into y_part (disjoint slots, no races)
        #pragma unroll
        for (int nb = 0; nb < 8; ++nb) {
            const int col = wave*128 + nb*16 + lm;
            const float b2 = be2[e*DD + col];
            #pragma unroll
            for (int mb = 0; mb < 2; ++mb) {
                #pragma unroll
                for (int r2 = 0; r2 < 4; ++r2) {
                    const int m = mb*16 + quad*4 + r2;
                    const int bt = toks[m];
                    if (bt >= 0)
                        y_part[(size_t)bt*DD + col] = tws[m] * (c[mb][nb][r2] + b2);
                }
            }
        }
        __syncthreads();   // protect toks/Xp/Hp reuse across items
    }
}

// ---------------------------------------------------------------------------
// reduce_y: y[t][:] = sum over a < nslot[t] of y_part[t*4+a][:]
// Grid-stride over NT*128 float4s (RGRID blocks — Guideline 11 cap).
// ---------------------------------------------------------------------------
__global__ __launch_bounds__(256) void reduce_y(
    const float* __restrict__ y_part, const int* __restrict__ nslot,
    float* __restrict__ y)
{
    for (int idx = blockIdx.x * 256 + threadIdx.x; idx < NT*128;
         idx += RGRID * 256) {
        const int t  = idx >> 7;
        const int c4 = idx & 127;
        const int ns = nslot[t];
        float4 s = make_float4(0.f, 0.f, 0.f, 0.f);
        const float* p = y_part + ((size_t)t*4)*DD + c4*4;
        for (int a = 0; a < ns; ++a) {
            float4 v = *(const float4*)(p + (size_t)a*DD);
            s.x += v.x; s.y += v.y; s.z += v.z; s.w += v.w;
        }
        *(float4*)(y + (size_t)t*DD + c4*4) = s;
    }
}

// ---------------------------------------------------------------------------
// Legacy expert GEMM v3 (fallback, fp32 weights + y atomics).
// ---------------------------------------------------------------------------
__global__ __launch_bounds__(256) void expert_mfma3(
    const float* __restrict__ hidden,
    const float* __restrict__ We1, const float* __restrict__ be1,
    const float* __restrict__ We2, const float* __restrict__ be2,
    const int* __restrict__ bucket_tok, const float* __restrict__ bucket_w,
    const int* __restrict__ counts,
    float* __restrict__ y)
{
    const int e    = blockIdx.x & 31;
    const int tile = blockIdx.x >> 5;
    const int cnt  = counts[e*CPAD];
    const int r0   = tile * TM;
    if (r0 >= cnt) return;
    const int nrow = min(TM, cnt - r0);
    const int tid  = threadIdx.x;
    const int wave = tid >> 6;
    const int lane = tid & 63;
    const int lm   = lane & 15;
    const int quad = lane >> 4;

    __shared__ short Xp[64 * XC_STRIDE];
    __shared__ short Hp[32 * XC_STRIDE];
    __shared__ int   toks[TM];
    __shared__ float tws[TM];

    if (tid < TM) {
        if (tid < nrow) {
            toks[tid] = bucket_tok[e*NT + r0 + tid] >> 2;   // decode token
            tws[tid]  = bucket_w[e*NT + r0 + tid];
        } else { toks[tid] = -1; tws[tid] = 0.f; }
    }
    __syncthreads();

    {
        const int xr = tid >> 3;
        const int xk = tid & 7;
        const int tk = toks[xr];
        const float* src = hidden + (size_t)(tk < 0 ? 0 : tk)*DD;
        #pragma unroll
        for (int i = 0; i < 8; ++i) {
            const int k8 = xk + 8*i;
            float4 v0 = make_float4(0.f,0.f,0.f,0.f), v1 = v0;
            if (tk >= 0) {
                v0 = *(const float4*)(src + k8*8);
                v1 = *(const float4*)(src + k8*8 + 4);
            }
            U4S8 cv;
            cv.u[0] = pk2(v0.x, v0.y); cv.u[1] = pk2(v0.z, v0.w);
            cv.u[2] = pk2(v1.x, v1.y); cv.u[3] = pk2(v1.z, v1.w);
            *(short8*)(&Xp[k8 * XC_STRIDE + xr * 8]) = cv.s;
        }
    }
    __syncthreads();

    floatx4 acc[2][4];
    #pragma unroll
    for (int mb = 0; mb < 2; ++mb)
        #pragma unroll
        for (int nb = 0; nb < 4; ++nb)
            acc[mb][nb] = (floatx4){0.f, 0.f, 0.f, 0.f};

    const float* W1 = We1 + (size_t)e * DD * DHC;

    for (int i = 0; i < 16; ++i) {
        const int k8 = i*4 + quad;
        short8 a0 = *(const short8*)(&Xp[k8 * XC_STRIDE + lm * 8]);
        short8 a1 = *(const short8*)(&Xp[k8 * XC_STRIDE + (16 + lm) * 8]);
        float wreg[4][8];
        #pragma unroll
        for (int nb = 0; nb < 4; ++nb) {
            const float* s = W1 + (size_t)(k8*8)*DHC + wave*64 + nb*16 + lm;
            #pragma unroll
            for (int j = 0; j < 8; ++j) wreg[nb][j] = s[(size_t)j*DHC];
        }
        #pragma unroll
        for (int nb = 0; nb < 4; ++nb) {
            U4S8 cv;
            cv.u[0] = pk2(wreg[nb][0], wreg[nb][1]);
            cv.u[1] = pk2(wreg[nb][2], wreg[nb][3]);
            cv.u[2] = pk2(wreg[nb][4], wreg[nb][5]);
            cv.u[3] = pk2(wreg[nb][6], wreg[nb][7]);
            acc[0][nb] = mfma16(a0, cv.s, acc[0][nb]);
            acc[1][nb] = mfma16(a1, cv.s, acc[1][nb]);
        }
    }

    #pragma unroll
    for (int nb = 0; nb < 4; ++nb) {
        const int h = wave*64 + nb*16 + lm;
        const float b1 = be1[e*DHC + h];
        #pragma unroll
        for (int mb = 0; mb < 2; ++mb) {
            #pragma unroll
            for (int r = 0; r < 4; r += 2) {
                const int m0 = mb*16 + quad*4 + r;
                unsigned u = pk2(gelu_exact(acc[mb][nb][r]   + b1),
                                 gelu_exact(acc[mb][nb][r+1] + b1));
                Hp[(h >> 3) * XC_STRIDE + m0 * 8 + (h & 7)]     = (short)(u & 0xffff);
                Hp[(h >> 3) * XC_STRIDE + (m0+1) * 8 + (h & 7)] = (short)(u >> 16);
            }
        }
    }
    __syncthreads();

    floatx4 c[2][8];
    #pragma unroll
    for (int mb = 0; mb < 2; ++mb)
        #pragma unroll
        for (int nb = 0; nb < 8; ++nb)
            c[mb][nb] = (floatx4){0.f, 0.f, 0.f, 0.f};

    const float* W2 = We2 + (size_t)e * DHC * DD;

    for (int i = 0; i < 8; ++i) {
        const int k8 = i*4 + quad;
        short8 a0 = *(const short8*)(&Hp[k8 * XC_STRIDE + lm * 8]);
        short8 a1 = *(const short8*)(&Hp[k8 * XC_STRIDE + (16 + lm) * 8]);
        #pragma unroll
        for (int half = 0; half < 2; ++half) {
            float wreg[4][8];
            #pragma unroll
            for (int nb4 = 0; nb4 < 4; ++nb4) {
                const int n = wave*128 + (half*4 + nb4)*16 + lm;
                const float* s = W2 + (size_t)(k8*8)*DD + n;
                #pragma unroll
                for (int j = 0; j < 8; ++j) wreg[nb4][j] = s[(size_t)j*DD];
            }
            #pragma unroll
            for (int nb4 = 0; nb4 < 4; ++nb4) {
                const int nb = half*4 + nb4;
                U4S8 cv;
                cv.u[0] = pk2(wreg[nb4][0], wreg[nb4][1]);
                cv.u[1] = pk2(wreg[nb4][2], wreg[nb4][3]);
                cv.u[2] = pk2(wreg[nb4][4], wreg[nb4][5]);
                cv.u[3] = pk2(wreg[nb4][6], wreg[nb4][7]);
                c[0][nb] = mfma16(a0, cv.s, c[0][nb]);
                c[1][nb] = mfma16(a1, cv.s, c[1][nb]);
            }
        }
    }

    #pragma unroll
    for (int nb = 0; nb < 8; ++nb) {
        const int col = wave*128 + nb*16 + lm;
        const float b2 = be2[e*DD + col];
        #pragma unroll
        for (int mb = 0; mb < 2; ++mb) {
            #pragma unroll
            for (int r = 0; r < 4; ++r) {
                const int m = mb*16 + quad*4 + r;
                const int tk = toks[m];
                if (tk >= 0)
                    atomicAdd(&y[(size_t)tk*DD + col], tws[m] * (c[mb][nb][r] + b2));
            }
        }
    }
}

extern "C" void kernel_launch(void* const* d_in, const int* in_sizes, int n_in,
                              void* d_out, int out_size, void* d_ws, size_t ws_size,
                              hipStream_t stream) {
    const float* hidden = (const float*)d_in[0];
    const float* feat   = (const float*)d_in[1];
    // d_in[2] = valid_mask (unused)
    const float* Wr1    = (const float*)d_in[3];
    const float* br1    = (const float*)d_in[4];
    const float* Wr2    = (const float*)d_in[5];
    const float* br2    = (const float*)d_in[6];
    const float* Wfe    = (const float*)d_in[7];
    const float* bfe    = (const float*)d_in[8];
    const float* Win_h  = (const float*)d_in[9];
    const float* Win_f  = (const float*)d_in[10];
    const float* bin_b  = (const float*)d_in[11];
    const float* We1    = (const float*)d_in[12];
    const float* be1    = (const float*)d_in[13];
    const float* We2    = (const float*)d_in[14];
    const float* be2    = (const float*)d_in[15];
    float* y = (float*)d_out;

    // workspace layout
    char* ws = (char*)d_ws;
    int*   bucket_tok = (int*)ws;    ws += (size_t)EEC*NT*sizeof(int);      // 512 KB
    float* bucket_w   = (float*)ws;  ws += (size_t)EEC*NT*sizeof(float);    // 512 KB
    int*   counts     = (int*)ws;    ws += (size_t)EEC*CPAD*sizeof(int);    // 4 KB (padded)
    float* WinT       = (float*)ws;  ws += (size_t)DD*EEC*sizeof(float);    // 64 KB
    float* M2         = (float*)ws;  ws += 512;
    float* c2b        = (float*)ws;  ws += 256;
    int*   nslot      = (int*)ws;    ws += (size_t)NT*sizeof(int);          // 16 KB
    size_t base_used  = (size_t)(ws - (char*)d_ws);

    // fast-path extras: packed bf16 weights (16 MB) + fp32 partials (32 MB)
    short* Wp1    = (short*)ws;
    short* Wp2    = Wp1 + (size_t)EEC*DD*DHC;
    float* y_part = (float*)(Wp2 + (size_t)EEC*DHC*DD);
    size_t need_fast = base_used
                     + 2*(size_t)EEC*DD*DHC*sizeof(short)
                     + (size_t)NT*4*DD*sizeof(float);
    const bool fast = (ws_size >= need_fast);

    // prep also zeros counts (block 65) — no memset launch needed
    prep_kernel<<<66, 256, 0, stream>>>(Win_h, Win_f, Wfe, bfe, bin_b,
                                        WinT, M2, c2b, counts);

    if (fast) {
        // route blocks [0,512) + pack blocks [512,4608), 256 threads each.
        route_and_pack<<<RBLK + PBLK, 256, 0, stream>>>(
            hidden, feat, Wr1, br1, Wr2, br2, WinT, M2, c2b,
            bucket_tok, bucket_w, counts, nslot,
            We1, We2, Wp1, Wp2);

        expert_mfma7<<<EGRID, 256, 0, stream>>>(hidden, Wp1, be1, Wp2, be2,
                                                bucket_tok, bucket_w, counts,
                                                y_part);

        reduce_y<<<RGRID, 256, 0, stream>>>(y_part, nslot, y);
    } else {
        hipMemsetAsync(y, 0, (size_t)NT*DD*sizeof(float), stream);

        // route only (no pack blocks); Wp pointers unused.
        route_and_pack<<<RBLK, 256, 0, stream>>>(
            hidden, feat, Wr1, br1, Wr2, br2, WinT, M2, c2b,
            bucket_tok, bucket_w, counts, nslot,
            We1, We2, (short*)nullptr, (short*)nullptr);

        expert_mfma3<<<(NT/TM)*EEC, 256, 0, stream>>>(hidden, We1, be1, We2, be2,
                                                      bucket_tok, bucket_w, counts, y);
    }
}